// Round 5
// baseline (899.631 us; speedup 1.0000x reference)
//
#include <hip/hip_runtime.h>

// Inputs/outputs FLOAT32 per the reference. bf16 internally for MFMA (raw u16).
typedef unsigned short u16;
typedef unsigned int u32;
typedef __attribute__((ext_vector_type(8))) short short8;   // MFMA A/B frag
typedef __attribute__((ext_vector_type(4))) float f32x4;    // MFMA C/D frag

__device__ inline u16 f32_to_bf16(float f) {          // RNE (cold paths only)
  u32 u = __float_as_uint(f);
  u += 0x7fffu + ((u >> 16) & 1u);
  return (u16)(u >> 16);
}
__device__ inline float bf16_to_f32(u16 s) {
  return __uint_as_float(((u32)s) << 16);
}

#if __has_builtin(__builtin_amdgcn_exp2f)
#define EXP2F(x) __builtin_amdgcn_exp2f(x)
#else
#define EXP2F(x) exp2f(x)
#endif

// pack top-16 of two f32 words: out = (hi16(b)<<16) | hi16(a)  (trunc-to-bf16 pair)
__device__ inline u32 pack_hi16(u32 a, u32 b) {
  return __builtin_amdgcn_perm(b, a, 0x07060302u);
}
// 8 f32 (a=elems0..3, b=4..7) -> bf16x8 via truncation
__device__ inline uint4 pack_bf16_8(const uint4 a, const uint4 b) {
  uint4 r;
  r.x = pack_hi16(a.x, a.y);
  r.y = pack_hi16(a.z, a.w);
  r.z = pack_hi16(b.x, b.y);
  r.w = pack_hi16(b.z, b.w);
  return r;
}
// 8 f32 -> hi/lo bf16 planes. hi=trunc; lo=trunc(v-hi) (v-hi exact, Sterbenz).
__device__ inline void split8(const uint4 a, const uint4 b, uint4& hi, uint4& lo) {
  u32 u[8] = {a.x, a.y, a.z, a.w, b.x, b.y, b.z, b.w};
  u32 l[8];
#pragma unroll
  for (int j = 0; j < 8; ++j)
    l[j] = __float_as_uint(__uint_as_float(u[j]) - __uint_as_float(u[j] & 0xffff0000u));
  hi.x = pack_hi16(u[0], u[1]); hi.y = pack_hi16(u[2], u[3]);
  hi.z = pack_hi16(u[4], u[5]); hi.w = pack_hi16(u[6], u[7]);
  lo.x = pack_hi16(l[0], l[1]); lo.y = pack_hi16(l[2], l[3]);
  lo.z = pack_hi16(l[4], l[5]); lo.w = pack_hi16(l[6], l[7]);
}

// ---------------------------------------------------------------------------
// Weight repack + f32 -> bf16 hi/lo planes (RNE; one-time). j = d*48 + k*16 + h.
__global__ void repack_w(const float* __restrict__ Wqkv, const float* __restrict__ Wtqkv,
                         const float* __restrict__ Wout,
                         u16* __restrict__ Wtq_hi, u16* __restrict__ Wtq_lo,
                         u16* __restrict__ Wk_hi,  u16* __restrict__ Wk_lo,
                         u16* __restrict__ Wv_hi,  u16* __restrict__ Woutb) {
  int r = blockIdx.x;              // 0..4095
  int part = r >> 10;
  int rr = r & 1023;
  int h = rr >> 6, d = rr & 63;
  const float* src;
  u16 *dh, *dl = nullptr;
  if (part == 0)      { src = Wtqkv + (size_t)(d * 48 + h) * 1024;      dh = Wtq_hi + (size_t)rr * 1024; dl = Wtq_lo + (size_t)rr * 1024; }
  else if (part == 1) { src = Wqkv  + (size_t)(d * 48 + 16 + h) * 1024; dh = Wk_hi  + (size_t)rr * 1024; dl = Wk_lo  + (size_t)rr * 1024; }
  else if (part == 2) { src = Wqkv  + (size_t)(d * 48 + 32 + h) * 1024; dh = Wv_hi  + (size_t)rr * 1024; }
  else                { src = Wout  + (size_t)rr * 1024;                dh = Woutb  + (size_t)rr * 1024; }
  int c = threadIdx.x * 4;
  f32x4 v = *(const f32x4*)&src[c];
  u32 hv[4], lv[4];
#pragma unroll
  for (int j = 0; j < 4; ++j) {
    u16 hb = f32_to_bf16(v[j]);
    hv[j] = hb;
    lv[j] = f32_to_bf16(v[j] - bf16_to_f32(hb));
  }
  uint2 ho; ho.x = hv[0] | (hv[1] << 16); ho.y = hv[2] | (hv[3] << 16);
  *(uint2*)&dh[c] = ho;
  if (dl) {
    uint2 lo; lo.x = lv[0] | (lv[1] << 16); lo.y = lv[2] | (lv[3] << 16);
    *(uint2*)&dl[c] = lo;
  }
}

// ---------------------------------------------------------------------------
// Fused projection GEMM, prefetch 2-barrier K-loop. grid (256,3) = 768 blocks.
// job 0: Q = tx @ Wtq^T * qscale -> Qhi/Qlo  (hilo, 3 MFMA)
// job 1: K = x  @ Wk^T           -> Khi/Klo  (hilo, 3 MFMA)
// job 2: Vt = Wv @ x^T           -> Vt[feat][t] bf16 (1 MFMA)
__global__ __launch_bounds__(256, 3)
void proj_fused(const float* __restrict__ x, const float* __restrict__ tx,
                const u16* __restrict__ Wtq_hi, const u16* __restrict__ Wtq_lo,
                const u16* __restrict__ Wk_hi,  const u16* __restrict__ Wk_lo,
                const u16* __restrict__ Wv_hi,
                u16* __restrict__ Qhi, u16* __restrict__ Qlo,
                u16* __restrict__ Khi, u16* __restrict__ Klo,
                u16* __restrict__ Vt, float qscale) {
  __shared__ __align__(16) u16 Ahs[128][40];
  __shared__ __align__(16) u16 Als[128][40];
  __shared__ __align__(16) u16 Bhs[128][40];
  __shared__ __align__(16) u16 Bls[128][40];
  const int tid = threadIdx.x;
  const int wid = tid >> 6, lane = tid & 63;
  const int g = lane >> 4, l16 = lane & 15;
  const int job = blockIdx.y;
  const int tile = blockIdx.x;
  const int wm = (wid & 1) * 64, wn = (wid >> 1) * 64;
  const int K = 1024;

  int m0, n0, N;
  const float* Af;                 // f32 operand
  const u16 *Bh = nullptr, *Bl = nullptr;
  if (job == 0) { m0 = (tile >> 3) * 128; n0 = (tile & 7) * 128; N = 1024; Af = tx; Bh = Wtq_hi; Bl = Wtq_lo; }
  else if (job == 1) { m0 = (tile >> 3) * 128; n0 = (tile & 7) * 128; N = 1024; Af = x; Bh = Wk_hi; Bl = Wk_lo; }
  else { m0 = (tile >> 5) * 128; n0 = (tile & 31) * 128; N = 4096; Af = x; Bh = Wv_hi; }

  f32x4 acc[4][4];
  const f32x4 zero4 = {0.f, 0.f, 0.f, 0.f};
#pragma unroll
  for (int i = 0; i < 4; ++i)
#pragma unroll
    for (int j = 0; j < 4; ++j) acc[i][j] = zero4;

  uint4 pF[2][2];   // f32 data (A for jobs 0/1; B for job 2)
  uint4 pU1[2];     // u16 data (Bh for jobs 0/1; Wv for job 2)
  uint4 pU2[2];     // Bl (jobs 0/1 only)

  // prologue: load k0=0
#pragma unroll
  for (int r = 0; r < 2; ++r) {
    int idx = tid + r * 256;
    int row = idx >> 2, col = (idx & 3) * 8;
    if (job != 2) {
      const float* ap = &Af[(size_t)(m0 + row) * K + col];
      pF[r][0] = *(const uint4*)ap;
      pF[r][1] = *(const uint4*)(ap + 4);
      pU1[r] = *(const uint4*)&Bh[(size_t)(n0 + row) * K + col];
      pU2[r] = *(const uint4*)&Bl[(size_t)(n0 + row) * K + col];
    } else {
      pU1[r] = *(const uint4*)&Bh[(size_t)(m0 + row) * K + col];
      const float* bp = &Af[(size_t)(n0 + row) * K + col];
      pF[r][0] = *(const uint4*)bp;
      pF[r][1] = *(const uint4*)(bp + 4);
    }
  }

  for (int k0 = 0; k0 < K; k0 += 32) {
    __syncthreads();
    // store phase (convert from prefetched regs)
#pragma unroll
    for (int r = 0; r < 2; ++r) {
      int idx = tid + r * 256;
      int row = idx >> 2, col = (idx & 3) * 8;
      if (job != 2) {
        uint4 hi, lo;
        split8(pF[r][0], pF[r][1], hi, lo);
        *(uint4*)&Ahs[row][col] = hi;
        *(uint4*)&Als[row][col] = lo;
        *(uint4*)&Bhs[row][col] = pU1[r];
        *(uint4*)&Bls[row][col] = pU2[r];
      } else {
        *(uint4*)&Ahs[row][col] = pU1[r];
        *(uint4*)&Bhs[row][col] = pack_bf16_8(pF[r][0], pF[r][1]);
      }
    }
    __syncthreads();
    // issue next chunk's loads
    if (k0 + 32 < K) {
      int kn = k0 + 32;
#pragma unroll
      for (int r = 0; r < 2; ++r) {
        int idx = tid + r * 256;
        int row = idx >> 2, col = (idx & 3) * 8;
        if (job != 2) {
          const float* ap = &Af[(size_t)(m0 + row) * K + kn + col];
          pF[r][0] = *(const uint4*)ap;
          pF[r][1] = *(const uint4*)(ap + 4);
          pU1[r] = *(const uint4*)&Bh[(size_t)(n0 + row) * K + kn + col];
          pU2[r] = *(const uint4*)&Bl[(size_t)(n0 + row) * K + kn + col];
        } else {
          pU1[r] = *(const uint4*)&Bh[(size_t)(m0 + row) * K + kn + col];
          const float* bp = &Af[(size_t)(n0 + row) * K + kn + col];
          pF[r][0] = *(const uint4*)bp;
          pF[r][1] = *(const uint4*)(bp + 4);
        }
      }
    }
    // compute
    if (job != 2) {
      short8 ah[4], al[4], bh4[4], bl4[4];
#pragma unroll
      for (int mi = 0; mi < 4; ++mi) {
        ah[mi] = *(const short8*)&Ahs[wm + mi * 16 + l16][g * 8];
        al[mi] = *(const short8*)&Als[wm + mi * 16 + l16][g * 8];
      }
#pragma unroll
      for (int ni = 0; ni < 4; ++ni) {
        bh4[ni] = *(const short8*)&Bhs[wn + ni * 16 + l16][g * 8];
        bl4[ni] = *(const short8*)&Bls[wn + ni * 16 + l16][g * 8];
      }
#pragma unroll
      for (int mi = 0; mi < 4; ++mi)
#pragma unroll
        for (int ni = 0; ni < 4; ++ni) {
          acc[mi][ni] = __builtin_amdgcn_mfma_f32_16x16x32_bf16(ah[mi], bh4[ni], acc[mi][ni], 0, 0, 0);
          acc[mi][ni] = __builtin_amdgcn_mfma_f32_16x16x32_bf16(ah[mi], bl4[ni], acc[mi][ni], 0, 0, 0);
          acc[mi][ni] = __builtin_amdgcn_mfma_f32_16x16x32_bf16(al[mi], bh4[ni], acc[mi][ni], 0, 0, 0);
        }
    } else {
      short8 af[4], bfr[4];
#pragma unroll
      for (int mi = 0; mi < 4; ++mi)
        af[mi] = *(const short8*)&Ahs[wm + mi * 16 + l16][g * 8];
#pragma unroll
      for (int ni = 0; ni < 4; ++ni)
        bfr[ni] = *(const short8*)&Bhs[wn + ni * 16 + l16][g * 8];
#pragma unroll
      for (int mi = 0; mi < 4; ++mi)
#pragma unroll
        for (int ni = 0; ni < 4; ++ni)
          acc[mi][ni] = __builtin_amdgcn_mfma_f32_16x16x32_bf16(af[mi], bfr[ni], acc[mi][ni], 0, 0, 0);
    }
  }

  // Epilogue. C/D: col=l16 (n), row=g*4+reg (m).
  u16* Chi = (job == 0) ? Qhi : ((job == 1) ? Khi : Vt);
  u16* Clo = (job == 0) ? Qlo : Klo;
  float scale = (job == 0) ? qscale : 1.0f;
#pragma unroll
  for (int mi = 0; mi < 4; ++mi)
#pragma unroll
    for (int ni = 0; ni < 4; ++ni) {
      int row = m0 + wm + mi * 16 + g * 4;
      int col = n0 + wn + ni * 16 + l16;
#pragma unroll
      for (int r = 0; r < 4; ++r) {
        float v = acc[mi][ni][r] * scale;
        size_t o = (size_t)(row + r) * N + col;
        u32 uv = __float_as_uint(v);
        if (job != 2) {
          Chi[o] = (u16)(uv >> 16);
          float lo = v - __uint_as_float(uv & 0xffff0000u);
          Clo[o] = (u16)(__float_as_uint(lo) >> 16);
        } else {
          Chi[o] = (u16)(uv >> 16);
        }
      }
    }
}

// ---------------------------------------------------------------------------
// Final projection: C(f32) = A bf16 * B^T bf16, 128x64 tiles, prefetch loop.
__global__ __launch_bounds__(256)
void gemm_out(const u16* __restrict__ A, const u16* __restrict__ B,
              float* __restrict__ C, int M, int N, int K) {
  __shared__ __align__(16) u16 As[128][40];
  __shared__ __align__(16) u16 Bs[64][40];
  const int tid = threadIdx.x;
  const int wid = tid >> 6, lane = tid & 63;
  const int g = lane >> 4, l16 = lane & 15;
  const int m0 = blockIdx.y * 128, n0 = blockIdx.x * 64;
  const int wm = (wid & 1) * 64, wn = (wid >> 1) * 32;

  f32x4 acc[4][2];
  const f32x4 zero4 = {0.f, 0.f, 0.f, 0.f};
#pragma unroll
  for (int i = 0; i < 4; ++i)
#pragma unroll
    for (int j = 0; j < 2; ++j) acc[i][j] = zero4;

  uint4 pa[2], pb;
  const int rowA0 = tid >> 2, colA = (tid & 3) * 8;
  const int rowA1 = rowA0 + 64;
  const int rowB = tid >> 2, colB = (tid & 3) * 8;
  pa[0] = *(const uint4*)&A[(size_t)(m0 + rowA0) * K + colA];
  pa[1] = *(const uint4*)&A[(size_t)(m0 + rowA1) * K + colA];
  pb    = *(const uint4*)&B[(size_t)(n0 + rowB) * K + colB];

  for (int k0 = 0; k0 < K; k0 += 32) {
    __syncthreads();
    *(uint4*)&As[rowA0][colA] = pa[0];
    *(uint4*)&As[rowA1][colA] = pa[1];
    *(uint4*)&Bs[rowB][colB] = pb;
    __syncthreads();
    if (k0 + 32 < K) {
      pa[0] = *(const uint4*)&A[(size_t)(m0 + rowA0) * K + k0 + 32 + colA];
      pa[1] = *(const uint4*)&A[(size_t)(m0 + rowA1) * K + k0 + 32 + colA];
      pb    = *(const uint4*)&B[(size_t)(n0 + rowB) * K + k0 + 32 + colB];
    }
    short8 af[4], bfr[2];
#pragma unroll
    for (int mi = 0; mi < 4; ++mi)
      af[mi] = *(const short8*)&As[wm + mi * 16 + l16][g * 8];
#pragma unroll
    for (int ni = 0; ni < 2; ++ni)
      bfr[ni] = *(const short8*)&Bs[wn + ni * 16 + l16][g * 8];
#pragma unroll
    for (int mi = 0; mi < 4; ++mi)
#pragma unroll
      for (int ni = 0; ni < 2; ++ni)
        acc[mi][ni] = __builtin_amdgcn_mfma_f32_16x16x32_bf16(af[mi], bfr[ni], acc[mi][ni], 0, 0, 0);
  }
#pragma unroll
  for (int mi = 0; mi < 4; ++mi)
#pragma unroll
    for (int ni = 0; ni < 2; ++ni) {
      int row = m0 + wm + mi * 16 + g * 4;
      int col = n0 + wn + ni * 16 + l16;
#pragma unroll
      for (int r = 0; r < 4; ++r)
        C[(size_t)(row + r) * N + col] = acc[mi][ni][r];
    }
}

// ---------------------------------------------------------------------------
// Flash attention v4: q-tile 64 (4 waves x 16 q), single-buffered LDS (38 KB ->
// 4 blocks/CU = 16 waves), 2 barriers/chunk, register prefetch of next chunk
// issued before compute. Row-sums via all-ones V rows (5th PV n-tile).
__global__ __launch_bounds__(256, 4)
void attn_fwd(const u16* __restrict__ Qhi, const u16* __restrict__ Qlo,
              const u16* __restrict__ Khi, const u16* __restrict__ Klo,
              const u16* __restrict__ Vt, u16* __restrict__ O) {
  const int blk = blockIdx.x;              // 1024 blocks
  const int qb = blk & 31, bh = blk >> 5;
  const int h = bh & 15, b = bh >> 4;
  const int t0 = qb * 64;
  const int tid = threadIdx.x, wid = tid >> 6, lane = tid & 63;
  const int g = lane >> 4, l16 = lane & 15;

  __shared__ __align__(16) u16 Ksh[64][72];   // keys x d
  __shared__ __align__(16) u16 Ksl[64][72];
  __shared__ __align__(16) u16 Vs[80][72];    // d x keys; rows 64..79 = ones
  __shared__ __align__(16) u16 Ps[4][16][72]; // per-wave P

  for (int i = tid; i < 16 * 72; i += 256)
    Vs[64 + i / 72][i % 72] = 0x3f80;

  // Persistent Q frags: rows t0 + wid*16 + l16, k = ks*32 + g*8 + j
  short8 qh[2], ql[2];
#pragma unroll
  for (int ks = 0; ks < 2; ++ks) {
    size_t qo = (size_t)(b * 2048 + t0 + wid * 16 + l16) * 1024 + h * 64 + ks * 32 + g * 8;
    qh[ks] = *(const short8*)&Qhi[qo];
    ql[ks] = *(const short8*)&Qlo[qo];
  }

  float mrow[4];
#pragma unroll
  for (int r = 0; r < 4; ++r) mrow[r] = -1.0e30f;
  const f32x4 zero4 = {0.f, 0.f, 0.f, 0.f};
  f32x4 acc[5];                    // [4] = row-sum (ones tile)
#pragma unroll
  for (int dn = 0; dn < 5; ++dn) acc[dn] = zero4;

  const size_t kbase = (size_t)(b * 2048) * 1024 + h * 64;
  const size_t vbase = (size_t)(h * 64) * 4096 + b * 2048;
  const int gr = tid & 7;
  const int srow = tid >> 3;               // 0..31

  // prologue: prefetch chunk 0
  uint4 nk[2], nl[2], nv[2];
#pragma unroll
  for (int pp = 0; pp < 2; ++pp) {
    int row = srow + pp * 32;
    size_t go = kbase + (size_t)row * 1024 + gr * 8;
    nk[pp] = *(const uint4*)&Khi[go];
    nl[pp] = *(const uint4*)&Klo[go];
    nv[pp] = *(const uint4*)&Vt[vbase + (size_t)row * 4096 + gr * 8];
  }

  for (int i = 0; i < 32; ++i) {
    __syncthreads();   // all waves done reading previous chunk
#pragma unroll
    for (int pp = 0; pp < 2; ++pp) {
      int row = srow + pp * 32;
      *(uint4*)&Ksh[row][gr * 8] = nk[pp];
      *(uint4*)&Ksl[row][gr * 8] = nl[pp];
      *(uint4*)&Vs[row][gr * 8] = nv[pp];
    }
    __syncthreads();   // staged data visible
    if (i < 31) {
      int j0n = (i + 1) * 64;
#pragma unroll
      for (int pp = 0; pp < 2; ++pp) {
        int row = srow + pp * 32;
        size_t go = kbase + (size_t)(j0n + row) * 1024 + gr * 8;
        nk[pp] = *(const uint4*)&Khi[go];
        nl[pp] = *(const uint4*)&Klo[go];
        nv[pp] = *(const uint4*)&Vt[vbase + (size_t)row * 4096 + j0n + gr * 8];
      }
    }

    // Scores (log2 domain; Q pre-scaled by 8*log2e)
    f32x4 s[4];
#pragma unroll
    for (int n = 0; n < 4; ++n) s[n] = zero4;
#pragma unroll
    for (int ks = 0; ks < 2; ++ks)
#pragma unroll
      for (int n = 0; n < 4; ++n) {
        short8 kh = *(const short8*)&Ksh[n * 16 + l16][ks * 32 + g * 8];
        short8 kl = *(const short8*)&Ksl[n * 16 + l16][ks * 32 + g * 8];
        s[n] = __builtin_amdgcn_mfma_f32_16x16x32_bf16(qh[ks], kh, s[n], 0, 0, 0);
        s[n] = __builtin_amdgcn_mfma_f32_16x16x32_bf16(ql[ks], kh, s[n], 0, 0, 0);
        s[n] = __builtin_amdgcn_mfma_f32_16x16x32_bf16(qh[ks], kl, s[n], 0, 0, 0);
      }

    // Online softmax (max only; sums via ones rows). Row = g*4+r.
#pragma unroll
    for (int r = 0; r < 4; ++r) {
      float cm = fmaxf(fmaxf(s[0][r], s[1][r]), fmaxf(s[2][r], s[3][r]));
      cm = fmaxf(cm, __shfl_xor(cm, 1));
      cm = fmaxf(cm, __shfl_xor(cm, 2));
      cm = fmaxf(cm, __shfl_xor(cm, 4));
      cm = fmaxf(cm, __shfl_xor(cm, 8));
      float mnew = fmaxf(mrow[r], cm);
      float al = EXP2F(mrow[r] - mnew);
      mrow[r] = mnew;
#pragma unroll
      for (int dn = 0; dn < 5; ++dn) acc[dn][r] *= al;
      int qr = g * 4 + r;
#pragma unroll
      for (int n = 0; n < 4; ++n) {
        float pv = EXP2F(s[n][r] - mnew);
        Ps[wid][qr][n * 16 + l16] = (u16)(__float_as_uint(pv) >> 16);
      }
    }

    // PV: P A-frag [m=q=l16][k=key]; Vs B-frag [n=d][k=key]
#pragma unroll
    for (int ks2 = 0; ks2 < 2; ++ks2) {
      short8 pa = *(const short8*)&Ps[wid][l16][ks2 * 32 + g * 8];
#pragma unroll
      for (int dn = 0; dn < 5; ++dn) {
        short8 vb = *(const short8*)&Vs[dn * 16 + l16][ks2 * 32 + g * 8];
        acc[dn] = __builtin_amdgcn_mfma_f32_16x16x32_bf16(pa, vb, acc[dn], 0, 0, 0);
      }
    }
  }

  // Epilogue: O[b, t, h*64+d] bf16 (trunc); l = acc[4]
#pragma unroll
  for (int r = 0; r < 4; ++r) {
    float inv = 1.f / acc[4][r];
    int row = t0 + wid * 16 + g * 4 + r;
    size_t base = (size_t)(b * 2048 + row) * 1024 + h * 64;
#pragma unroll
    for (int dn = 0; dn < 4; ++dn)
      O[base + dn * 16 + l16] = (u16)(__float_as_uint(acc[dn][r] * inv) >> 16);
  }
}

// ---------------------------------------------------------------------------
extern "C" void kernel_launch(void* const* d_in, const int* in_sizes, int n_in,
                              void* d_out, int out_size, void* d_ws, size_t ws_size,
                              hipStream_t stream) {
  const float* x     = (const float*)d_in[0];
  const float* tx    = (const float*)d_in[1];
  const float* Wqkv  = (const float*)d_in[2];
  const float* Wtqkv = (const float*)d_in[3];
  const float* Wout  = (const float*)d_in[4];
  float* out = (float*)d_out;

  // workspace (peak 52 MB):
  //  0 Wtq_hi | 2 Wtq_lo | 4 Wk_hi | 6 Wk_lo | 8 Wv_hi | 10 Wout_b  (MB)
  //  12 Qhi 8 | 20 Qlo 8 | 28 Khi 8 | 36 Klo 8 | 44 Vt 8
  //  Ob (8MB) aliases 0-8 (weight planes dead after projections)
  char* ws = (char*)d_ws;
  const size_t MB = 1048576;
  u16* Wtq_hi = (u16*)(ws + 0 * MB);
  u16* Wtq_lo = (u16*)(ws + 2 * MB);
  u16* Wk_hi  = (u16*)(ws + 4 * MB);
  u16* Wk_lo  = (u16*)(ws + 6 * MB);
  u16* Wv_hi  = (u16*)(ws + 8 * MB);
  u16* Woutb  = (u16*)(ws + 10 * MB);
  u16* Qhi    = (u16*)(ws + 12 * MB);
  u16* Qlo    = (u16*)(ws + 20 * MB);
  u16* Khi    = (u16*)(ws + 28 * MB);
  u16* Klo    = (u16*)(ws + 36 * MB);
  u16* Vt     = (u16*)(ws + 44 * MB);
  u16* Ob     = (u16*)(ws + 0 * MB);
  if (ws_size < 52 * MB) return;

  const float QSCALE = 8.0f * 1.4426950408889634f;  // sqrt(d)=8, log2(e)

  repack_w<<<4096, 256, 0, stream>>>(Wqkv, Wtqkv, Wout,
                                     Wtq_hi, Wtq_lo, Wk_hi, Wk_lo, Wv_hi, Woutb);
  proj_fused<<<dim3(256, 3), 256, 0, stream>>>(x, tx, Wtq_hi, Wtq_lo, Wk_hi, Wk_lo,
                                               Wv_hi, Qhi, Qlo, Khi, Klo, Vt, QSCALE);
  attn_fwd<<<1024, 256, 0, stream>>>(Qhi, Qlo, Khi, Klo, Vt, Ob);
  gemm_out<<<dim3(16, 32), 256, 0, stream>>>(Ob, Woutb, out, 4096, 1024, 1024);
}

// Round 6
// 531.390 us; speedup vs baseline: 1.6930x; 1.6930x over previous
//
#include <hip/hip_runtime.h>

// Inputs/outputs FLOAT32 per the reference. bf16 internally for MFMA (raw u16).
// NOTE: no min-waves arg in __launch_bounds__ anywhere — round 5 showed that
// capping VGPRs below natural allocation (84/128) causes catastrophic scratch
// spills (WRITE_SIZE 955 MB, 444 us proj). Let the allocator breathe.
typedef unsigned short u16;
typedef unsigned int u32;
typedef __attribute__((ext_vector_type(8))) short short8;   // MFMA A/B frag
typedef __attribute__((ext_vector_type(4))) float f32x4;    // MFMA C/D frag

__device__ inline u16 f32_to_bf16(float f) {          // RNE (cold paths only)
  u32 u = __float_as_uint(f);
  u += 0x7fffu + ((u >> 16) & 1u);
  return (u16)(u >> 16);
}
__device__ inline float bf16_to_f32(u16 s) {
  return __uint_as_float(((u32)s) << 16);
}

#if __has_builtin(__builtin_amdgcn_exp2f)
#define EXP2F(x) __builtin_amdgcn_exp2f(x)
#else
#define EXP2F(x) exp2f(x)
#endif

// pack top-16 of two f32 words: out = (hi16(b)<<16) | hi16(a)
__device__ inline u32 pack_hi16(u32 a, u32 b) {
  return __builtin_amdgcn_perm(b, a, 0x07060302u);
}
// 8 f32 -> bf16x8 via truncation
__device__ inline uint4 pack_bf16_8(const uint4 a, const uint4 b) {
  uint4 r;
  r.x = pack_hi16(a.x, a.y);
  r.y = pack_hi16(a.z, a.w);
  r.z = pack_hi16(b.x, b.y);
  r.w = pack_hi16(b.z, b.w);
  return r;
}
// 8 f32 -> hi/lo bf16 planes. hi=trunc; lo=trunc(v-hi) (v-hi exact, Sterbenz).
__device__ inline void split8(const uint4 a, const uint4 b, uint4& hi, uint4& lo) {
  u32 u[8] = {a.x, a.y, a.z, a.w, b.x, b.y, b.z, b.w};
  u32 l[8];
#pragma unroll
  for (int j = 0; j < 8; ++j)
    l[j] = __float_as_uint(__uint_as_float(u[j]) - __uint_as_float(u[j] & 0xffff0000u));
  hi.x = pack_hi16(u[0], u[1]); hi.y = pack_hi16(u[2], u[3]);
  hi.z = pack_hi16(u[4], u[5]); hi.w = pack_hi16(u[6], u[7]);
  lo.x = pack_hi16(l[0], l[1]); lo.y = pack_hi16(l[2], l[3]);
  lo.z = pack_hi16(l[4], l[5]); lo.w = pack_hi16(l[6], l[7]);
}

// ---------------------------------------------------------------------------
// Weight repack + f32 -> bf16 hi/lo planes (RNE; one-time). j = d*48 + k*16 + h.
__global__ void repack_w(const float* __restrict__ Wqkv, const float* __restrict__ Wtqkv,
                         const float* __restrict__ Wout,
                         u16* __restrict__ Wtq_hi, u16* __restrict__ Wtq_lo,
                         u16* __restrict__ Wk_hi,  u16* __restrict__ Wk_lo,
                         u16* __restrict__ Wv_hi,  u16* __restrict__ Woutb) {
  int r = blockIdx.x;              // 0..4095
  int part = r >> 10;
  int rr = r & 1023;
  int h = rr >> 6, d = rr & 63;
  const float* src;
  u16 *dh, *dl = nullptr;
  if (part == 0)      { src = Wtqkv + (size_t)(d * 48 + h) * 1024;      dh = Wtq_hi + (size_t)rr * 1024; dl = Wtq_lo + (size_t)rr * 1024; }
  else if (part == 1) { src = Wqkv  + (size_t)(d * 48 + 16 + h) * 1024; dh = Wk_hi  + (size_t)rr * 1024; dl = Wk_lo  + (size_t)rr * 1024; }
  else if (part == 2) { src = Wqkv  + (size_t)(d * 48 + 32 + h) * 1024; dh = Wv_hi  + (size_t)rr * 1024; }
  else                { src = Wout  + (size_t)rr * 1024;                dh = Woutb  + (size_t)rr * 1024; }
  int c = threadIdx.x * 4;
  f32x4 v = *(const f32x4*)&src[c];
  u32 hv[4], lv[4];
#pragma unroll
  for (int j = 0; j < 4; ++j) {
    u16 hb = f32_to_bf16(v[j]);
    hv[j] = hb;
    lv[j] = f32_to_bf16(v[j] - bf16_to_f32(hb));
  }
  uint2 ho; ho.x = hv[0] | (hv[1] << 16); ho.y = hv[2] | (hv[3] << 16);
  *(uint2*)&dh[c] = ho;
  if (dl) {
    uint2 lo; lo.x = lv[0] | (lv[1] << 16); lo.y = lv[2] | (lv[3] << 16);
    *(uint2*)&dl[c] = lo;
  }
}

// ---------------------------------------------------------------------------
// Fused projection GEMM, prefetch 2-barrier K-loop. grid (256,3) = 768 blocks.
// job 0: Q = tx @ Wtq^T * qscale -> Qhi/Qlo  (hilo, 3 MFMA)
// job 1: K = x  @ Wk^T           -> Khi/Klo  (hilo, 3 MFMA)
// job 2: Vt = Wv @ x^T           -> Vt[feat][t] bf16 (1 MFMA)
__global__ __launch_bounds__(256)
void proj_fused(const float* __restrict__ x, const float* __restrict__ tx,
                const u16* __restrict__ Wtq_hi, const u16* __restrict__ Wtq_lo,
                const u16* __restrict__ Wk_hi,  const u16* __restrict__ Wk_lo,
                const u16* __restrict__ Wv_hi,
                u16* __restrict__ Qhi, u16* __restrict__ Qlo,
                u16* __restrict__ Khi, u16* __restrict__ Klo,
                u16* __restrict__ Vt, float qscale) {
  __shared__ __align__(16) u16 Ahs[128][40];
  __shared__ __align__(16) u16 Als[128][40];
  __shared__ __align__(16) u16 Bhs[128][40];
  __shared__ __align__(16) u16 Bls[128][40];
  const int tid = threadIdx.x;
  const int wid = tid >> 6, lane = tid & 63;
  const int g = lane >> 4, l16 = lane & 15;
  const int job = blockIdx.y;
  const int tile = blockIdx.x;
  const int wm = (wid & 1) * 64, wn = (wid >> 1) * 64;
  const int K = 1024;

  int m0, n0, N;
  const float* Af;                 // f32 operand
  const u16 *Bh = nullptr, *Bl = nullptr;
  if (job == 0) { m0 = (tile >> 3) * 128; n0 = (tile & 7) * 128; N = 1024; Af = tx; Bh = Wtq_hi; Bl = Wtq_lo; }
  else if (job == 1) { m0 = (tile >> 3) * 128; n0 = (tile & 7) * 128; N = 1024; Af = x; Bh = Wk_hi; Bl = Wk_lo; }
  else { m0 = (tile >> 5) * 128; n0 = (tile & 31) * 128; N = 4096; Af = x; Bh = Wv_hi; }

  f32x4 acc[4][4];
  const f32x4 zero4 = {0.f, 0.f, 0.f, 0.f};
#pragma unroll
  for (int i = 0; i < 4; ++i)
#pragma unroll
    for (int j = 0; j < 4; ++j) acc[i][j] = zero4;

  uint4 pF[2][2];   // f32 data (A for jobs 0/1; B for job 2)
  uint4 pU1[2];     // u16 data (Bh for jobs 0/1; Wv for job 2)
  uint4 pU2[2];     // Bl (jobs 0/1 only)

  // prologue: load k0=0
#pragma unroll
  for (int r = 0; r < 2; ++r) {
    int idx = tid + r * 256;
    int row = idx >> 2, col = (idx & 3) * 8;
    if (job != 2) {
      const float* ap = &Af[(size_t)(m0 + row) * K + col];
      pF[r][0] = *(const uint4*)ap;
      pF[r][1] = *(const uint4*)(ap + 4);
      pU1[r] = *(const uint4*)&Bh[(size_t)(n0 + row) * K + col];
      pU2[r] = *(const uint4*)&Bl[(size_t)(n0 + row) * K + col];
    } else {
      pU1[r] = *(const uint4*)&Bh[(size_t)(m0 + row) * K + col];
      const float* bp = &Af[(size_t)(n0 + row) * K + col];
      pF[r][0] = *(const uint4*)bp;
      pF[r][1] = *(const uint4*)(bp + 4);
    }
  }

  for (int k0 = 0; k0 < K; k0 += 32) {
    __syncthreads();
    // store phase (convert from prefetched regs)
#pragma unroll
    for (int r = 0; r < 2; ++r) {
      int idx = tid + r * 256;
      int row = idx >> 2, col = (idx & 3) * 8;
      if (job != 2) {
        uint4 hi, lo;
        split8(pF[r][0], pF[r][1], hi, lo);
        *(uint4*)&Ahs[row][col] = hi;
        *(uint4*)&Als[row][col] = lo;
        *(uint4*)&Bhs[row][col] = pU1[r];
        *(uint4*)&Bls[row][col] = pU2[r];
      } else {
        *(uint4*)&Ahs[row][col] = pU1[r];
        *(uint4*)&Bhs[row][col] = pack_bf16_8(pF[r][0], pF[r][1]);
      }
    }
    __syncthreads();
    // issue next chunk's loads (overlap with MFMA below)
    if (k0 + 32 < K) {
      int kn = k0 + 32;
#pragma unroll
      for (int r = 0; r < 2; ++r) {
        int idx = tid + r * 256;
        int row = idx >> 2, col = (idx & 3) * 8;
        if (job != 2) {
          const float* ap = &Af[(size_t)(m0 + row) * K + kn + col];
          pF[r][0] = *(const uint4*)ap;
          pF[r][1] = *(const uint4*)(ap + 4);
          pU1[r] = *(const uint4*)&Bh[(size_t)(n0 + row) * K + kn + col];
          pU2[r] = *(const uint4*)&Bl[(size_t)(n0 + row) * K + kn + col];
        } else {
          pU1[r] = *(const uint4*)&Bh[(size_t)(m0 + row) * K + kn + col];
          const float* bp = &Af[(size_t)(n0 + row) * K + kn + col];
          pF[r][0] = *(const uint4*)bp;
          pF[r][1] = *(const uint4*)(bp + 4);
        }
      }
    }
    // compute
    if (job != 2) {
      short8 ah[4], al[4], bh4[4], bl4[4];
#pragma unroll
      for (int mi = 0; mi < 4; ++mi) {
        ah[mi] = *(const short8*)&Ahs[wm + mi * 16 + l16][g * 8];
        al[mi] = *(const short8*)&Als[wm + mi * 16 + l16][g * 8];
      }
#pragma unroll
      for (int ni = 0; ni < 4; ++ni) {
        bh4[ni] = *(const short8*)&Bhs[wn + ni * 16 + l16][g * 8];
        bl4[ni] = *(const short8*)&Bls[wn + ni * 16 + l16][g * 8];
      }
#pragma unroll
      for (int mi = 0; mi < 4; ++mi)
#pragma unroll
        for (int ni = 0; ni < 4; ++ni) {
          acc[mi][ni] = __builtin_amdgcn_mfma_f32_16x16x32_bf16(ah[mi], bh4[ni], acc[mi][ni], 0, 0, 0);
          acc[mi][ni] = __builtin_amdgcn_mfma_f32_16x16x32_bf16(ah[mi], bl4[ni], acc[mi][ni], 0, 0, 0);
          acc[mi][ni] = __builtin_amdgcn_mfma_f32_16x16x32_bf16(al[mi], bh4[ni], acc[mi][ni], 0, 0, 0);
        }
    } else {
      short8 af[4], bfr[4];
#pragma unroll
      for (int mi = 0; mi < 4; ++mi)
        af[mi] = *(const short8*)&Ahs[wm + mi * 16 + l16][g * 8];
#pragma unroll
      for (int ni = 0; ni < 4; ++ni)
        bfr[ni] = *(const short8*)&Bhs[wn + ni * 16 + l16][g * 8];
#pragma unroll
      for (int mi = 0; mi < 4; ++mi)
#pragma unroll
        for (int ni = 0; ni < 4; ++ni)
          acc[mi][ni] = __builtin_amdgcn_mfma_f32_16x16x32_bf16(af[mi], bfr[ni], acc[mi][ni], 0, 0, 0);
    }
  }

  // Epilogue. C/D: col=l16 (n), row=g*4+reg (m).
  u16* Chi = (job == 0) ? Qhi : ((job == 1) ? Khi : Vt);
  u16* Clo = (job == 0) ? Qlo : Klo;
  float scale = (job == 0) ? qscale : 1.0f;
#pragma unroll
  for (int mi = 0; mi < 4; ++mi)
#pragma unroll
    for (int ni = 0; ni < 4; ++ni) {
      int row = m0 + wm + mi * 16 + g * 4;
      int col = n0 + wn + ni * 16 + l16;
#pragma unroll
      for (int r = 0; r < 4; ++r) {
        float v = acc[mi][ni][r] * scale;
        size_t o = (size_t)(row + r) * N + col;
        u32 uv = __float_as_uint(v);
        if (job != 2) {
          Chi[o] = (u16)(uv >> 16);
          float lo = v - __uint_as_float(uv & 0xffff0000u);
          Clo[o] = (u16)(__float_as_uint(lo) >> 16);
        } else {
          Chi[o] = (u16)(uv >> 16);
        }
      }
    }
}

// ---------------------------------------------------------------------------
// Final projection: C(f32) = A bf16 * B^T bf16, 128x64 tiles, prefetch loop.
__global__ __launch_bounds__(256)
void gemm_out(const u16* __restrict__ A, const u16* __restrict__ B,
              float* __restrict__ C, int M, int N, int K) {
  __shared__ __align__(16) u16 As[128][40];
  __shared__ __align__(16) u16 Bs[64][40];
  const int tid = threadIdx.x;
  const int wid = tid >> 6, lane = tid & 63;
  const int g = lane >> 4, l16 = lane & 15;
  const int m0 = blockIdx.y * 128, n0 = blockIdx.x * 64;
  const int wm = (wid & 1) * 64, wn = (wid >> 1) * 32;

  f32x4 acc[4][2];
  const f32x4 zero4 = {0.f, 0.f, 0.f, 0.f};
#pragma unroll
  for (int i = 0; i < 4; ++i)
#pragma unroll
    for (int j = 0; j < 2; ++j) acc[i][j] = zero4;

  uint4 pa[2], pb;
  const int rowA0 = tid >> 2, colA = (tid & 3) * 8;
  const int rowA1 = rowA0 + 64;
  const int rowB = tid >> 2, colB = (tid & 3) * 8;
  pa[0] = *(const uint4*)&A[(size_t)(m0 + rowA0) * K + colA];
  pa[1] = *(const uint4*)&A[(size_t)(m0 + rowA1) * K + colA];
  pb    = *(const uint4*)&B[(size_t)(n0 + rowB) * K + colB];

  for (int k0 = 0; k0 < K; k0 += 32) {
    __syncthreads();
    *(uint4*)&As[rowA0][colA] = pa[0];
    *(uint4*)&As[rowA1][colA] = pa[1];
    *(uint4*)&Bs[rowB][colB] = pb;
    __syncthreads();
    if (k0 + 32 < K) {
      pa[0] = *(const uint4*)&A[(size_t)(m0 + rowA0) * K + k0 + 32 + colA];
      pa[1] = *(const uint4*)&A[(size_t)(m0 + rowA1) * K + k0 + 32 + colA];
      pb    = *(const uint4*)&B[(size_t)(n0 + rowB) * K + k0 + 32 + colB];
    }
    short8 af[4], bfr[2];
#pragma unroll
    for (int mi = 0; mi < 4; ++mi)
      af[mi] = *(const short8*)&As[wm + mi * 16 + l16][g * 8];
#pragma unroll
    for (int ni = 0; ni < 2; ++ni)
      bfr[ni] = *(const short8*)&Bs[wn + ni * 16 + l16][g * 8];
#pragma unroll
    for (int mi = 0; mi < 4; ++mi)
#pragma unroll
      for (int ni = 0; ni < 2; ++ni)
        acc[mi][ni] = __builtin_amdgcn_mfma_f32_16x16x32_bf16(af[mi], bfr[ni], acc[mi][ni], 0, 0, 0);
  }
#pragma unroll
  for (int mi = 0; mi < 4; ++mi)
#pragma unroll
    for (int ni = 0; ni < 2; ++ni) {
      int row = m0 + wm + mi * 16 + g * 4;
      int col = n0 + wn + ni * 16 + l16;
#pragma unroll
      for (int r = 0; r < 4; ++r)
        C[(size_t)(row + r) * N + col] = acc[mi][ni][r];
    }
}

// ---------------------------------------------------------------------------
// Flash attention v5: q-tile 64 (4 waves x 16 q), single-buffered LDS (38 KB
// allows 4 blocks/CU if VGPR <= 128 — left to the allocator, NOT forced),
// 2 barriers/chunk, register prefetch of next chunk issued before compute.
// Row-sums via all-ones V rows (5th PV n-tile).
__global__ __launch_bounds__(256)
void attn_fwd(const u16* __restrict__ Qhi, const u16* __restrict__ Qlo,
              const u16* __restrict__ Khi, const u16* __restrict__ Klo,
              const u16* __restrict__ Vt, u16* __restrict__ O) {
  const int blk = blockIdx.x;              // 1024 blocks
  const int qb = blk & 31, bh = blk >> 5;
  const int h = bh & 15, b = bh >> 4;
  const int t0 = qb * 64;
  const int tid = threadIdx.x, wid = tid >> 6, lane = tid & 63;
  const int g = lane >> 4, l16 = lane & 15;

  __shared__ __align__(16) u16 Ksh[64][72];   // keys x d
  __shared__ __align__(16) u16 Ksl[64][72];
  __shared__ __align__(16) u16 Vs[80][72];    // d x keys; rows 64..79 = ones
  __shared__ __align__(16) u16 Ps[4][16][72]; // per-wave P

  for (int i = tid; i < 16 * 72; i += 256)
    Vs[64 + i / 72][i % 72] = 0x3f80;

  // Persistent Q frags: rows t0 + wid*16 + l16, k = ks*32 + g*8 + j
  short8 qh[2], ql[2];
#pragma unroll
  for (int ks = 0; ks < 2; ++ks) {
    size_t qo = (size_t)(b * 2048 + t0 + wid * 16 + l16) * 1024 + h * 64 + ks * 32 + g * 8;
    qh[ks] = *(const short8*)&Qhi[qo];
    ql[ks] = *(const short8*)&Qlo[qo];
  }

  float mrow[4];
#pragma unroll
  for (int r = 0; r < 4; ++r) mrow[r] = -1.0e30f;
  const f32x4 zero4 = {0.f, 0.f, 0.f, 0.f};
  f32x4 acc[5];                    // [4] = row-sum (ones tile)
#pragma unroll
  for (int dn = 0; dn < 5; ++dn) acc[dn] = zero4;

  const size_t kbase = (size_t)(b * 2048) * 1024 + h * 64;
  const size_t vbase = (size_t)(h * 64) * 4096 + b * 2048;
  const int gr = tid & 7;
  const int srow = tid >> 3;               // 0..31

  // prologue: prefetch chunk 0
  uint4 nk[2], nl[2], nv[2];
#pragma unroll
  for (int pp = 0; pp < 2; ++pp) {
    int row = srow + pp * 32;
    size_t go = kbase + (size_t)row * 1024 + gr * 8;
    nk[pp] = *(const uint4*)&Khi[go];
    nl[pp] = *(const uint4*)&Klo[go];
    nv[pp] = *(const uint4*)&Vt[vbase + (size_t)row * 4096 + gr * 8];
  }

  for (int i = 0; i < 32; ++i) {
    __syncthreads();   // all waves done reading previous chunk
#pragma unroll
    for (int pp = 0; pp < 2; ++pp) {
      int row = srow + pp * 32;
      *(uint4*)&Ksh[row][gr * 8] = nk[pp];
      *(uint4*)&Ksl[row][gr * 8] = nl[pp];
      *(uint4*)&Vs[row][gr * 8] = nv[pp];
    }
    __syncthreads();   // staged data visible
    if (i < 31) {
      int j0n = (i + 1) * 64;
#pragma unroll
      for (int pp = 0; pp < 2; ++pp) {
        int row = srow + pp * 32;
        size_t go = kbase + (size_t)(j0n + row) * 1024 + gr * 8;
        nk[pp] = *(const uint4*)&Khi[go];
        nl[pp] = *(const uint4*)&Klo[go];
        nv[pp] = *(const uint4*)&Vt[vbase + (size_t)row * 4096 + j0n + gr * 8];
      }
    }

    // Scores (log2 domain; Q pre-scaled by 8*log2e)
    f32x4 s[4];
#pragma unroll
    for (int n = 0; n < 4; ++n) s[n] = zero4;
#pragma unroll
    for (int ks = 0; ks < 2; ++ks)
#pragma unroll
      for (int n = 0; n < 4; ++n) {
        short8 kh = *(const short8*)&Ksh[n * 16 + l16][ks * 32 + g * 8];
        short8 kl = *(const short8*)&Ksl[n * 16 + l16][ks * 32 + g * 8];
        s[n] = __builtin_amdgcn_mfma_f32_16x16x32_bf16(qh[ks], kh, s[n], 0, 0, 0);
        s[n] = __builtin_amdgcn_mfma_f32_16x16x32_bf16(ql[ks], kh, s[n], 0, 0, 0);
        s[n] = __builtin_amdgcn_mfma_f32_16x16x32_bf16(qh[ks], kl, s[n], 0, 0, 0);
      }

    // Online softmax (max only; sums via ones rows). Row = g*4+r.
#pragma unroll
    for (int r = 0; r < 4; ++r) {
      float cm = fmaxf(fmaxf(s[0][r], s[1][r]), fmaxf(s[2][r], s[3][r]));
      cm = fmaxf(cm, __shfl_xor(cm, 1));
      cm = fmaxf(cm, __shfl_xor(cm, 2));
      cm = fmaxf(cm, __shfl_xor(cm, 4));
      cm = fmaxf(cm, __shfl_xor(cm, 8));
      float mnew = fmaxf(mrow[r], cm);
      float al = EXP2F(mrow[r] - mnew);
      mrow[r] = mnew;
#pragma unroll
      for (int dn = 0; dn < 5; ++dn) acc[dn][r] *= al;
      int qr = g * 4 + r;
#pragma unroll
      for (int n = 0; n < 4; ++n) {
        float pv = EXP2F(s[n][r] - mnew);
        Ps[wid][qr][n * 16 + l16] = (u16)(__float_as_uint(pv) >> 16);
      }
    }

    // PV: P A-frag [m=q=l16][k=key]; Vs B-frag [n=d][k=key]
#pragma unroll
    for (int ks2 = 0; ks2 < 2; ++ks2) {
      short8 pa = *(const short8*)&Ps[wid][l16][ks2 * 32 + g * 8];
#pragma unroll
      for (int dn = 0; dn < 5; ++dn) {
        short8 vb = *(const short8*)&Vs[dn * 16 + l16][ks2 * 32 + g * 8];
        acc[dn] = __builtin_amdgcn_mfma_f32_16x16x32_bf16(pa, vb, acc[dn], 0, 0, 0);
      }
    }
  }

  // Epilogue: O[b, t, h*64+d] bf16 (trunc); l = acc[4]
#pragma unroll
  for (int r = 0; r < 4; ++r) {
    float inv = 1.f / acc[4][r];
    int row = t0 + wid * 16 + g * 4 + r;
    size_t base = (size_t)(b * 2048 + row) * 1024 + h * 64;
#pragma unroll
    for (int dn = 0; dn < 4; ++dn)
      O[base + dn * 16 + l16] = (u16)(__float_as_uint(acc[dn][r] * inv) >> 16);
  }
}

// ---------------------------------------------------------------------------
extern "C" void kernel_launch(void* const* d_in, const int* in_sizes, int n_in,
                              void* d_out, int out_size, void* d_ws, size_t ws_size,
                              hipStream_t stream) {
  const float* x     = (const float*)d_in[0];
  const float* tx    = (const float*)d_in[1];
  const float* Wqkv  = (const float*)d_in[2];
  const float* Wtqkv = (const float*)d_in[3];
  const float* Wout  = (const float*)d_in[4];
  float* out = (float*)d_out;

  // workspace (peak 52 MB):
  //  0 Wtq_hi | 2 Wtq_lo | 4 Wk_hi | 6 Wk_lo | 8 Wv_hi | 10 Wout_b  (MB)
  //  12 Qhi 8 | 20 Qlo 8 | 28 Khi 8 | 36 Klo 8 | 44 Vt 8
  //  Ob (8MB) aliases 0-8 (weight planes dead after projections)
  char* ws = (char*)d_ws;
  const size_t MB = 1048576;
  u16* Wtq_hi = (u16*)(ws + 0 * MB);
  u16* Wtq_lo = (u16*)(ws + 2 * MB);
  u16* Wk_hi  = (u16*)(ws + 4 * MB);
  u16* Wk_lo  = (u16*)(ws + 6 * MB);
  u16* Wv_hi  = (u16*)(ws + 8 * MB);
  u16* Woutb  = (u16*)(ws + 10 * MB);
  u16* Qhi    = (u16*)(ws + 12 * MB);
  u16* Qlo    = (u16*)(ws + 20 * MB);
  u16* Khi    = (u16*)(ws + 28 * MB);
  u16* Klo    = (u16*)(ws + 36 * MB);
  u16* Vt     = (u16*)(ws + 44 * MB);
  u16* Ob     = (u16*)(ws + 0 * MB);
  if (ws_size < 52 * MB) return;

  const float QSCALE = 8.0f * 1.4426950408889634f;  // sqrt(d)=8, log2(e)

  repack_w<<<4096, 256, 0, stream>>>(Wqkv, Wtqkv, Wout,
                                     Wtq_hi, Wtq_lo, Wk_hi, Wk_lo, Wv_hi, Woutb);
  proj_fused<<<dim3(256, 3), 256, 0, stream>>>(x, tx, Wtq_hi, Wtq_lo, Wk_hi, Wk_lo,
                                               Wv_hi, Qhi, Qlo, Khi, Klo, Vt, QSCALE);
  attn_fwd<<<1024, 256, 0, stream>>>(Qhi, Qlo, Khi, Klo, Vt, Ob);
  gemm_out<<<dim3(16, 32), 256, 0, stream>>>(Ob, Woutb, out, 4096, 1024, 1024);
}

// Round 7
// 512.116 us; speedup vs baseline: 1.7567x; 1.0376x over previous
//
#include <hip/hip_runtime.h>

// Inputs/outputs FLOAT32 per the reference. bf16 internally for MFMA (raw u16).
// REGISTER-ALLOCATION NOTE (r5/r6 post-mortems): the AMDGPU scheduler picks its
// own occupancy TARGET independent of __launch_bounds__ min-waves, and will
// spill to scratch to reach it (r6 attn: VGPR=64, WRITE_SIZE=794MB; r5 proj:
// VGPR=84, 955MB). Clamp the target from above with amdgpu_waves_per_eu(min,max).
typedef unsigned short u16;
typedef unsigned int u32;
typedef __attribute__((ext_vector_type(8))) short short8;   // MFMA A/B frag
typedef __attribute__((ext_vector_type(4))) float f32x4;    // MFMA C/D frag

__device__ inline u16 f32_to_bf16(float f) {          // RNE (cold paths only)
  u32 u = __float_as_uint(f);
  u += 0x7fffu + ((u >> 16) & 1u);
  return (u16)(u >> 16);
}
__device__ inline float bf16_to_f32(u16 s) {
  return __uint_as_float(((u32)s) << 16);
}

#if __has_builtin(__builtin_amdgcn_exp2f)
#define EXP2F(x) __builtin_amdgcn_exp2f(x)
#else
#define EXP2F(x) exp2f(x)
#endif

// pack top-16 of two f32 words: out = (hi16(b)<<16) | hi16(a)
__device__ inline u32 pack_hi16(u32 a, u32 b) {
  return __builtin_amdgcn_perm(b, a, 0x07060302u);
}
// 8 f32 -> bf16x8 via truncation
__device__ inline uint4 pack_bf16_8(const uint4 a, const uint4 b) {
  uint4 r;
  r.x = pack_hi16(a.x, a.y);
  r.y = pack_hi16(a.z, a.w);
  r.z = pack_hi16(b.x, b.y);
  r.w = pack_hi16(b.z, b.w);
  return r;
}
// 8 f32 -> hi/lo bf16 planes. hi=trunc; lo=trunc(v-hi) (v-hi exact, Sterbenz).
__device__ inline void split8(const uint4 a, const uint4 b, uint4& hi, uint4& lo) {
  u32 u[8] = {a.x, a.y, a.z, a.w, b.x, b.y, b.z, b.w};
  u32 l[8];
#pragma unroll
  for (int j = 0; j < 8; ++j)
    l[j] = __float_as_uint(__uint_as_float(u[j]) - __uint_as_float(u[j] & 0xffff0000u));
  hi.x = pack_hi16(u[0], u[1]); hi.y = pack_hi16(u[2], u[3]);
  hi.z = pack_hi16(u[4], u[5]); hi.w = pack_hi16(u[6], u[7]);
  lo.x = pack_hi16(l[0], l[1]); lo.y = pack_hi16(l[2], l[3]);
  lo.z = pack_hi16(l[4], l[5]); lo.w = pack_hi16(l[6], l[7]);
}

// ---------------------------------------------------------------------------
// Weight repack + f32 -> bf16 hi/lo planes (RNE; one-time). j = d*48 + k*16 + h.
__global__ void repack_w(const float* __restrict__ Wqkv, const float* __restrict__ Wtqkv,
                         const float* __restrict__ Wout,
                         u16* __restrict__ Wtq_hi, u16* __restrict__ Wtq_lo,
                         u16* __restrict__ Wk_hi,  u16* __restrict__ Wk_lo,
                         u16* __restrict__ Wv_hi,  u16* __restrict__ Woutb) {
  int r = blockIdx.x;              // 0..4095
  int part = r >> 10;
  int rr = r & 1023;
  int h = rr >> 6, d = rr & 63;
  const float* src;
  u16 *dh, *dl = nullptr;
  if (part == 0)      { src = Wtqkv + (size_t)(d * 48 + h) * 1024;      dh = Wtq_hi + (size_t)rr * 1024; dl = Wtq_lo + (size_t)rr * 1024; }
  else if (part == 1) { src = Wqkv  + (size_t)(d * 48 + 16 + h) * 1024; dh = Wk_hi  + (size_t)rr * 1024; dl = Wk_lo  + (size_t)rr * 1024; }
  else if (part == 2) { src = Wqkv  + (size_t)(d * 48 + 32 + h) * 1024; dh = Wv_hi  + (size_t)rr * 1024; }
  else                { src = Wout  + (size_t)rr * 1024;                dh = Woutb  + (size_t)rr * 1024; }
  int c = threadIdx.x * 4;
  f32x4 v = *(const f32x4*)&src[c];
  u32 hv[4], lv[4];
#pragma unroll
  for (int j = 0; j < 4; ++j) {
    u16 hb = f32_to_bf16(v[j]);
    hv[j] = hb;
    lv[j] = f32_to_bf16(v[j] - bf16_to_f32(hb));
  }
  uint2 ho; ho.x = hv[0] | (hv[1] << 16); ho.y = hv[2] | (hv[3] << 16);
  *(uint2*)&dh[c] = ho;
  if (dl) {
    uint2 lo; lo.x = lv[0] | (lv[1] << 16); lo.y = lv[2] | (lv[3] << 16);
    *(uint2*)&dl[c] = lo;
  }
}

// ---------------------------------------------------------------------------
// Fused projection GEMM, prefetch 2-barrier K-loop. grid (256,3) = 768 blocks.
// job 0: Q = tx @ Wtq^T * qscale -> Qhi/Qlo  (hilo, 3 MFMA)
// job 1: K = x  @ Wk^T           -> Khi/Klo  (hilo, 3 MFMA)
// job 2: Vt = Wv @ x^T           -> Vt[feat][t] bf16 (1 MFMA)
// waves_per_eu(2,3): needs ~140 VGPR (prefetch 32 + acc 64 + addr) -> 3/EU.
__global__ __launch_bounds__(256) __attribute__((amdgpu_waves_per_eu(2, 3)))
void proj_fused(const float* __restrict__ x, const float* __restrict__ tx,
                const u16* __restrict__ Wtq_hi, const u16* __restrict__ Wtq_lo,
                const u16* __restrict__ Wk_hi,  const u16* __restrict__ Wk_lo,
                const u16* __restrict__ Wv_hi,
                u16* __restrict__ Qhi, u16* __restrict__ Qlo,
                u16* __restrict__ Khi, u16* __restrict__ Klo,
                u16* __restrict__ Vt, float qscale) {
  __shared__ __align__(16) u16 Ahs[128][40];
  __shared__ __align__(16) u16 Als[128][40];
  __shared__ __align__(16) u16 Bhs[128][40];
  __shared__ __align__(16) u16 Bls[128][40];
  const int tid = threadIdx.x;
  const int wid = tid >> 6, lane = tid & 63;
  const int g = lane >> 4, l16 = lane & 15;
  const int job = blockIdx.y;
  const int tile = blockIdx.x;
  const int wm = (wid & 1) * 64, wn = (wid >> 1) * 64;
  const int K = 1024;

  int m0, n0, N;
  const float* Af;                 // f32 operand
  const u16 *Bh = nullptr, *Bl = nullptr;
  if (job == 0) { m0 = (tile >> 3) * 128; n0 = (tile & 7) * 128; N = 1024; Af = tx; Bh = Wtq_hi; Bl = Wtq_lo; }
  else if (job == 1) { m0 = (tile >> 3) * 128; n0 = (tile & 7) * 128; N = 1024; Af = x; Bh = Wk_hi; Bl = Wk_lo; }
  else { m0 = (tile >> 5) * 128; n0 = (tile & 31) * 128; N = 4096; Af = x; Bh = Wv_hi; }

  f32x4 acc[4][4];
  const f32x4 zero4 = {0.f, 0.f, 0.f, 0.f};
#pragma unroll
  for (int i = 0; i < 4; ++i)
#pragma unroll
    for (int j = 0; j < 4; ++j) acc[i][j] = zero4;

  uint4 pF[2][2];   // f32 data (A for jobs 0/1; B for job 2)
  uint4 pU1[2];     // u16 data (Bh for jobs 0/1; Wv for job 2)
  uint4 pU2[2];     // Bl (jobs 0/1 only)

  // prologue: load k0=0
#pragma unroll
  for (int r = 0; r < 2; ++r) {
    int idx = tid + r * 256;
    int row = idx >> 2, col = (idx & 3) * 8;
    if (job != 2) {
      const float* ap = &Af[(size_t)(m0 + row) * K + col];
      pF[r][0] = *(const uint4*)ap;
      pF[r][1] = *(const uint4*)(ap + 4);
      pU1[r] = *(const uint4*)&Bh[(size_t)(n0 + row) * K + col];
      pU2[r] = *(const uint4*)&Bl[(size_t)(n0 + row) * K + col];
    } else {
      pU1[r] = *(const uint4*)&Bh[(size_t)(m0 + row) * K + col];
      const float* bp = &Af[(size_t)(n0 + row) * K + col];
      pF[r][0] = *(const uint4*)bp;
      pF[r][1] = *(const uint4*)(bp + 4);
    }
  }

  for (int k0 = 0; k0 < K; k0 += 32) {
    __syncthreads();
    // store phase (convert from prefetched regs)
#pragma unroll
    for (int r = 0; r < 2; ++r) {
      int idx = tid + r * 256;
      int row = idx >> 2, col = (idx & 3) * 8;
      if (job != 2) {
        uint4 hi, lo;
        split8(pF[r][0], pF[r][1], hi, lo);
        *(uint4*)&Ahs[row][col] = hi;
        *(uint4*)&Als[row][col] = lo;
        *(uint4*)&Bhs[row][col] = pU1[r];
        *(uint4*)&Bls[row][col] = pU2[r];
      } else {
        *(uint4*)&Ahs[row][col] = pU1[r];
        *(uint4*)&Bhs[row][col] = pack_bf16_8(pF[r][0], pF[r][1]);
      }
    }
    __syncthreads();
    // issue next chunk's loads (overlap with MFMA below)
    if (k0 + 32 < K) {
      int kn = k0 + 32;
#pragma unroll
      for (int r = 0; r < 2; ++r) {
        int idx = tid + r * 256;
        int row = idx >> 2, col = (idx & 3) * 8;
        if (job != 2) {
          const float* ap = &Af[(size_t)(m0 + row) * K + kn + col];
          pF[r][0] = *(const uint4*)ap;
          pF[r][1] = *(const uint4*)(ap + 4);
          pU1[r] = *(const uint4*)&Bh[(size_t)(n0 + row) * K + kn + col];
          pU2[r] = *(const uint4*)&Bl[(size_t)(n0 + row) * K + kn + col];
        } else {
          pU1[r] = *(const uint4*)&Bh[(size_t)(m0 + row) * K + kn + col];
          const float* bp = &Af[(size_t)(n0 + row) * K + kn + col];
          pF[r][0] = *(const uint4*)bp;
          pF[r][1] = *(const uint4*)(bp + 4);
        }
      }
    }
    // compute
    if (job != 2) {
      short8 ah[4], al[4], bh4[4], bl4[4];
#pragma unroll
      for (int mi = 0; mi < 4; ++mi) {
        ah[mi] = *(const short8*)&Ahs[wm + mi * 16 + l16][g * 8];
        al[mi] = *(const short8*)&Als[wm + mi * 16 + l16][g * 8];
      }
#pragma unroll
      for (int ni = 0; ni < 4; ++ni) {
        bh4[ni] = *(const short8*)&Bhs[wn + ni * 16 + l16][g * 8];
        bl4[ni] = *(const short8*)&Bls[wn + ni * 16 + l16][g * 8];
      }
#pragma unroll
      for (int mi = 0; mi < 4; ++mi)
#pragma unroll
        for (int ni = 0; ni < 4; ++ni) {
          acc[mi][ni] = __builtin_amdgcn_mfma_f32_16x16x32_bf16(ah[mi], bh4[ni], acc[mi][ni], 0, 0, 0);
          acc[mi][ni] = __builtin_amdgcn_mfma_f32_16x16x32_bf16(ah[mi], bl4[ni], acc[mi][ni], 0, 0, 0);
          acc[mi][ni] = __builtin_amdgcn_mfma_f32_16x16x32_bf16(al[mi], bh4[ni], acc[mi][ni], 0, 0, 0);
        }
    } else {
      short8 af[4], bfr[4];
#pragma unroll
      for (int mi = 0; mi < 4; ++mi)
        af[mi] = *(const short8*)&Ahs[wm + mi * 16 + l16][g * 8];
#pragma unroll
      for (int ni = 0; ni < 4; ++ni)
        bfr[ni] = *(const short8*)&Bhs[wn + ni * 16 + l16][g * 8];
#pragma unroll
      for (int mi = 0; mi < 4; ++mi)
#pragma unroll
        for (int ni = 0; ni < 4; ++ni)
          acc[mi][ni] = __builtin_amdgcn_mfma_f32_16x16x32_bf16(af[mi], bfr[ni], acc[mi][ni], 0, 0, 0);
    }
  }

  // Epilogue. C/D: col=l16 (n), row=g*4+reg (m).
  u16* Chi = (job == 0) ? Qhi : ((job == 1) ? Khi : Vt);
  u16* Clo = (job == 0) ? Qlo : Klo;
  float scale = (job == 0) ? qscale : 1.0f;
#pragma unroll
  for (int mi = 0; mi < 4; ++mi)
#pragma unroll
    for (int ni = 0; ni < 4; ++ni) {
      int row = m0 + wm + mi * 16 + g * 4;
      int col = n0 + wn + ni * 16 + l16;
#pragma unroll
      for (int r = 0; r < 4; ++r) {
        float v = acc[mi][ni][r] * scale;
        size_t o = (size_t)(row + r) * N + col;
        u32 uv = __float_as_uint(v);
        if (job != 2) {
          Chi[o] = (u16)(uv >> 16);
          float lo = v - __uint_as_float(uv & 0xffff0000u);
          Clo[o] = (u16)(__float_as_uint(lo) >> 16);
        } else {
          Chi[o] = (u16)(uv >> 16);
        }
      }
    }
}

// ---------------------------------------------------------------------------
// Final projection: C(f32) = A bf16 * B^T bf16, 128x64 tiles, prefetch loop.
__global__ __launch_bounds__(256) __attribute__((amdgpu_waves_per_eu(2, 4)))
void gemm_out(const u16* __restrict__ A, const u16* __restrict__ B,
              float* __restrict__ C, int M, int N, int K) {
  __shared__ __align__(16) u16 As[128][40];
  __shared__ __align__(16) u16 Bs[64][40];
  const int tid = threadIdx.x;
  const int wid = tid >> 6, lane = tid & 63;
  const int g = lane >> 4, l16 = lane & 15;
  const int m0 = blockIdx.y * 128, n0 = blockIdx.x * 64;
  const int wm = (wid & 1) * 64, wn = (wid >> 1) * 32;

  f32x4 acc[4][2];
  const f32x4 zero4 = {0.f, 0.f, 0.f, 0.f};
#pragma unroll
  for (int i = 0; i < 4; ++i)
#pragma unroll
    for (int j = 0; j < 2; ++j) acc[i][j] = zero4;

  uint4 pa[2], pb;
  const int rowA0 = tid >> 2, colA = (tid & 3) * 8;
  const int rowA1 = rowA0 + 64;
  const int rowB = tid >> 2, colB = (tid & 3) * 8;
  pa[0] = *(const uint4*)&A[(size_t)(m0 + rowA0) * K + colA];
  pa[1] = *(const uint4*)&A[(size_t)(m0 + rowA1) * K + colA];
  pb    = *(const uint4*)&B[(size_t)(n0 + rowB) * K + colB];

  for (int k0 = 0; k0 < K; k0 += 32) {
    __syncthreads();
    *(uint4*)&As[rowA0][colA] = pa[0];
    *(uint4*)&As[rowA1][colA] = pa[1];
    *(uint4*)&Bs[rowB][colB] = pb;
    __syncthreads();
    if (k0 + 32 < K) {
      pa[0] = *(const uint4*)&A[(size_t)(m0 + rowA0) * K + k0 + 32 + colA];
      pa[1] = *(const uint4*)&A[(size_t)(m0 + rowA1) * K + k0 + 32 + colA];
      pb    = *(const uint4*)&B[(size_t)(n0 + rowB) * K + k0 + 32 + colB];
    }
    short8 af[4], bfr[2];
#pragma unroll
    for (int mi = 0; mi < 4; ++mi)
      af[mi] = *(const short8*)&As[wm + mi * 16 + l16][g * 8];
#pragma unroll
    for (int ni = 0; ni < 2; ++ni)
      bfr[ni] = *(const short8*)&Bs[wn + ni * 16 + l16][g * 8];
#pragma unroll
    for (int mi = 0; mi < 4; ++mi)
#pragma unroll
      for (int ni = 0; ni < 2; ++ni)
        acc[mi][ni] = __builtin_amdgcn_mfma_f32_16x16x32_bf16(af[mi], bfr[ni], acc[mi][ni], 0, 0, 0);
  }
#pragma unroll
  for (int mi = 0; mi < 4; ++mi)
#pragma unroll
    for (int ni = 0; ni < 2; ++ni) {
      int row = m0 + wm + mi * 16 + g * 4;
      int col = n0 + wn + ni * 16 + l16;
#pragma unroll
      for (int r = 0; r < 4; ++r)
        C[(size_t)(row + r) * N + col] = acc[mi][ni][r];
    }
}

// ---------------------------------------------------------------------------
// Flash attention v6: q-tile 64 (4 waves x 16 q), single-buffered LDS (39 KB
// -> 4 blocks/CU), 2 barriers/chunk, register prefetch of next chunk.
// waves_per_eu(2,4): kernel needs ~105 VGPR; clamp stops the scheduler from
// targeting 8 waves/EU and spilling (r6: VGPR=64, 794MB scratch writes).
__global__ __launch_bounds__(256) __attribute__((amdgpu_waves_per_eu(2, 4)))
void attn_fwd(const u16* __restrict__ Qhi, const u16* __restrict__ Qlo,
              const u16* __restrict__ Khi, const u16* __restrict__ Klo,
              const u16* __restrict__ Vt, u16* __restrict__ O) {
  const int blk = blockIdx.x;              // 1024 blocks
  const int qb = blk & 31, bh = blk >> 5;
  const int h = bh & 15, b = bh >> 4;
  const int t0 = qb * 64;
  const int tid = threadIdx.x, wid = tid >> 6, lane = tid & 63;
  const int g = lane >> 4, l16 = lane & 15;

  __shared__ __align__(16) u16 Ksh[64][72];   // keys x d
  __shared__ __align__(16) u16 Ksl[64][72];
  __shared__ __align__(16) u16 Vs[80][72];    // d x keys; rows 64..79 = ones
  __shared__ __align__(16) u16 Ps[4][16][72]; // per-wave P

  for (int i = tid; i < 16 * 72; i += 256)
    Vs[64 + i / 72][i % 72] = 0x3f80;

  // Persistent Q frags: rows t0 + wid*16 + l16, k = ks*32 + g*8 + j
  short8 qh[2], ql[2];
#pragma unroll
  for (int ks = 0; ks < 2; ++ks) {
    size_t qo = (size_t)(b * 2048 + t0 + wid * 16 + l16) * 1024 + h * 64 + ks * 32 + g * 8;
    qh[ks] = *(const short8*)&Qhi[qo];
    ql[ks] = *(const short8*)&Qlo[qo];
  }

  float mrow[4];
#pragma unroll
  for (int r = 0; r < 4; ++r) mrow[r] = -1.0e30f;
  const f32x4 zero4 = {0.f, 0.f, 0.f, 0.f};
  f32x4 acc[5];                    // [4] = row-sum (ones tile)
#pragma unroll
  for (int dn = 0; dn < 5; ++dn) acc[dn] = zero4;

  const size_t kbase = (size_t)(b * 2048) * 1024 + h * 64;
  const size_t vbase = (size_t)(h * 64) * 4096 + b * 2048;
  const int gr = tid & 7;
  const int srow = tid >> 3;               // 0..31

  // prologue: prefetch chunk 0
  uint4 nk[2], nl[2], nv[2];
#pragma unroll
  for (int pp = 0; pp < 2; ++pp) {
    int row = srow + pp * 32;
    size_t go = kbase + (size_t)row * 1024 + gr * 8;
    nk[pp] = *(const uint4*)&Khi[go];
    nl[pp] = *(const uint4*)&Klo[go];
    nv[pp] = *(const uint4*)&Vt[vbase + (size_t)row * 4096 + gr * 8];
  }

  for (int i = 0; i < 32; ++i) {
    __syncthreads();   // all waves done reading previous chunk
#pragma unroll
    for (int pp = 0; pp < 2; ++pp) {
      int row = srow + pp * 32;
      *(uint4*)&Ksh[row][gr * 8] = nk[pp];
      *(uint4*)&Ksl[row][gr * 8] = nl[pp];
      *(uint4*)&Vs[row][gr * 8] = nv[pp];
    }
    __syncthreads();   // staged data visible
    if (i < 31) {
      int j0n = (i + 1) * 64;
#pragma unroll
      for (int pp = 0; pp < 2; ++pp) {
        int row = srow + pp * 32;
        size_t go = kbase + (size_t)(j0n + row) * 1024 + gr * 8;
        nk[pp] = *(const uint4*)&Khi[go];
        nl[pp] = *(const uint4*)&Klo[go];
        nv[pp] = *(const uint4*)&Vt[vbase + (size_t)row * 4096 + j0n + gr * 8];
      }
    }

    // Scores (log2 domain; Q pre-scaled by 8*log2e)
    f32x4 s[4];
#pragma unroll
    for (int n = 0; n < 4; ++n) s[n] = zero4;
#pragma unroll
    for (int ks = 0; ks < 2; ++ks)
#pragma unroll
      for (int n = 0; n < 4; ++n) {
        short8 kh = *(const short8*)&Ksh[n * 16 + l16][ks * 32 + g * 8];
        short8 kl = *(const short8*)&Ksl[n * 16 + l16][ks * 32 + g * 8];
        s[n] = __builtin_amdgcn_mfma_f32_16x16x32_bf16(qh[ks], kh, s[n], 0, 0, 0);
        s[n] = __builtin_amdgcn_mfma_f32_16x16x32_bf16(ql[ks], kh, s[n], 0, 0, 0);
        s[n] = __builtin_amdgcn_mfma_f32_16x16x32_bf16(qh[ks], kl, s[n], 0, 0, 0);
      }

    // Online softmax (max only; sums via ones rows). Row = g*4+r.
#pragma unroll
    for (int r = 0; r < 4; ++r) {
      float cm = fmaxf(fmaxf(s[0][r], s[1][r]), fmaxf(s[2][r], s[3][r]));
      cm = fmaxf(cm, __shfl_xor(cm, 1));
      cm = fmaxf(cm, __shfl_xor(cm, 2));
      cm = fmaxf(cm, __shfl_xor(cm, 4));
      cm = fmaxf(cm, __shfl_xor(cm, 8));
      float mnew = fmaxf(mrow[r], cm);
      float al = EXP2F(mrow[r] - mnew);
      mrow[r] = mnew;
#pragma unroll
      for (int dn = 0; dn < 5; ++dn) acc[dn][r] *= al;
      int qr = g * 4 + r;
#pragma unroll
      for (int n = 0; n < 4; ++n) {
        float pv = EXP2F(s[n][r] - mnew);
        Ps[wid][qr][n * 16 + l16] = (u16)(__float_as_uint(pv) >> 16);
      }
    }

    // PV: P A-frag [m=q=l16][k=key]; Vs B-frag [n=d][k=key]
#pragma unroll
    for (int ks2 = 0; ks2 < 2; ++ks2) {
      short8 pa = *(const short8*)&Ps[wid][l16][ks2 * 32 + g * 8];
#pragma unroll
      for (int dn = 0; dn < 5; ++dn) {
        short8 vb = *(const short8*)&Vs[dn * 16 + l16][ks2 * 32 + g * 8];
        acc[dn] = __builtin_amdgcn_mfma_f32_16x16x32_bf16(pa, vb, acc[dn], 0, 0, 0);
      }
    }
  }

  // Epilogue: O[b, t, h*64+d] bf16 (trunc); l = acc[4]
#pragma unroll
  for (int r = 0; r < 4; ++r) {
    float inv = 1.f / acc[4][r];
    int row = t0 + wid * 16 + g * 4 + r;
    size_t base = (size_t)(b * 2048 + row) * 1024 + h * 64;
#pragma unroll
    for (int dn = 0; dn < 4; ++dn)
      O[base + dn * 16 + l16] = (u16)(__float_as_uint(acc[dn][r] * inv) >> 16);
  }
}

// ---------------------------------------------------------------------------
extern "C" void kernel_launch(void* const* d_in, const int* in_sizes, int n_in,
                              void* d_out, int out_size, void* d_ws, size_t ws_size,
                              hipStream_t stream) {
  const float* x     = (const float*)d_in[0];
  const float* tx    = (const float*)d_in[1];
  const float* Wqkv  = (const float*)d_in[2];
  const float* Wtqkv = (const float*)d_in[3];
  const float* Wout  = (const float*)d_in[4];
  float* out = (float*)d_out;

  // workspace (peak 52 MB):
  //  0 Wtq_hi | 2 Wtq_lo | 4 Wk_hi | 6 Wk_lo | 8 Wv_hi | 10 Wout_b  (MB)
  //  12 Qhi 8 | 20 Qlo 8 | 28 Khi 8 | 36 Klo 8 | 44 Vt 8
  //  Ob (8MB) aliases 0-8 (weight planes dead after projections)
  char* ws = (char*)d_ws;
  const size_t MB = 1048576;
  u16* Wtq_hi = (u16*)(ws + 0 * MB);
  u16* Wtq_lo = (u16*)(ws + 2 * MB);
  u16* Wk_hi  = (u16*)(ws + 4 * MB);
  u16* Wk_lo  = (u16*)(ws + 6 * MB);
  u16* Wv_hi  = (u16*)(ws + 8 * MB);
  u16* Woutb  = (u16*)(ws + 10 * MB);
  u16* Qhi    = (u16*)(ws + 12 * MB);
  u16* Qlo    = (u16*)(ws + 20 * MB);
  u16* Khi    = (u16*)(ws + 28 * MB);
  u16* Klo    = (u16*)(ws + 36 * MB);
  u16* Vt     = (u16*)(ws + 44 * MB);
  u16* Ob     = (u16*)(ws + 0 * MB);
  if (ws_size < 52 * MB) return;

  const float QSCALE = 8.0f * 1.4426950408889634f;  // sqrt(d)=8, log2(e)

  repack_w<<<4096, 256, 0, stream>>>(Wqkv, Wtqkv, Wout,
                                     Wtq_hi, Wtq_lo, Wk_hi, Wk_lo, Wv_hi, Woutb);
  proj_fused<<<dim3(256, 3), 256, 0, stream>>>(x, tx, Wtq_hi, Wtq_lo, Wk_hi, Wk_lo,
                                               Wv_hi, Qhi, Qlo, Khi, Klo, Vt, QSCALE);
  attn_fwd<<<1024, 256, 0, stream>>>(Qhi, Qlo, Khi, Klo, Vt, Ob);
  gemm_out<<<dim3(16, 32), 256, 0, stream>>>(Ob, Woutb, out, 4096, 1024, 1024);
}

// Round 8
// 383.227 us; speedup vs baseline: 2.3475x; 1.3363x over previous
//
#include <hip/hip_runtime.h>

// Inputs/outputs FLOAT32 per the reference. bf16 internally for MFMA (raw u16).
// REGISTER-ALLOCATION HISTORY (r4-r7): the allocator's occupancy choice tracks
// kernel body + LDS size, not attributes. Small-LDS attn variants got squeezed
// to 64-68 VGPR and spilled ~550-800MB scratch. Fix here: eliminate staging
// registers entirely via global_load_lds (async DMA global->LDS, zero VGPRs).
typedef unsigned short u16;
typedef unsigned int u32;
typedef __attribute__((ext_vector_type(8))) short short8;   // MFMA A/B frag
typedef __attribute__((ext_vector_type(4))) float f32x4;    // MFMA C/D frag

__device__ inline u16 f32_to_bf16(float f) {          // RNE (cold paths only)
  u32 u = __float_as_uint(f);
  u += 0x7fffu + ((u >> 16) & 1u);
  return (u16)(u >> 16);
}
__device__ inline float bf16_to_f32(u16 s) {
  return __uint_as_float(((u32)s) << 16);
}

#if __has_builtin(__builtin_amdgcn_exp2f)
#define EXP2F(x) __builtin_amdgcn_exp2f(x)
#else
#define EXP2F(x) exp2f(x)
#endif

// async 16B global->LDS DMA (dest = wave-uniform LDS base + lane*16)
__device__ inline void dma16(const u16* gp, u16* lp) {
  __builtin_amdgcn_global_load_lds(
      (const __attribute__((address_space(1))) u32*)gp,
      (__attribute__((address_space(3))) u32*)lp, 16, 0, 0);
}

// pack top-16 of two f32 words: out = (hi16(b)<<16) | hi16(a)
__device__ inline u32 pack_hi16(u32 a, u32 b) {
  return __builtin_amdgcn_perm(b, a, 0x07060302u);
}
// 8 f32 -> bf16x8 via truncation
__device__ inline uint4 pack_bf16_8(const uint4 a, const uint4 b) {
  uint4 r;
  r.x = pack_hi16(a.x, a.y);
  r.y = pack_hi16(a.z, a.w);
  r.z = pack_hi16(b.x, b.y);
  r.w = pack_hi16(b.z, b.w);
  return r;
}
// 8 f32 -> hi/lo bf16 planes. hi=trunc; lo=trunc(v-hi) (v-hi exact, Sterbenz).
__device__ inline void split8(const uint4 a, const uint4 b, uint4& hi, uint4& lo) {
  u32 u[8] = {a.x, a.y, a.z, a.w, b.x, b.y, b.z, b.w};
  u32 l[8];
#pragma unroll
  for (int j = 0; j < 8; ++j)
    l[j] = __float_as_uint(__uint_as_float(u[j]) - __uint_as_float(u[j] & 0xffff0000u));
  hi.x = pack_hi16(u[0], u[1]); hi.y = pack_hi16(u[2], u[3]);
  hi.z = pack_hi16(u[4], u[5]); hi.w = pack_hi16(u[6], u[7]);
  lo.x = pack_hi16(l[0], l[1]); lo.y = pack_hi16(l[2], l[3]);
  lo.z = pack_hi16(l[4], l[5]); lo.w = pack_hi16(l[6], l[7]);
}

// ---------------------------------------------------------------------------
// Weight repack + f32 -> bf16 hi/lo planes (RNE; one-time). j = d*48 + k*16 + h.
__global__ void repack_w(const float* __restrict__ Wqkv, const float* __restrict__ Wtqkv,
                         const float* __restrict__ Wout,
                         u16* __restrict__ Wtq_hi, u16* __restrict__ Wtq_lo,
                         u16* __restrict__ Wk_hi,  u16* __restrict__ Wk_lo,
                         u16* __restrict__ Wv_hi,  u16* __restrict__ Woutb) {
  int r = blockIdx.x;              // 0..4095
  int part = r >> 10;
  int rr = r & 1023;
  int h = rr >> 6, d = rr & 63;
  const float* src;
  u16 *dh, *dl = nullptr;
  if (part == 0)      { src = Wtqkv + (size_t)(d * 48 + h) * 1024;      dh = Wtq_hi + (size_t)rr * 1024; dl = Wtq_lo + (size_t)rr * 1024; }
  else if (part == 1) { src = Wqkv  + (size_t)(d * 48 + 16 + h) * 1024; dh = Wk_hi  + (size_t)rr * 1024; dl = Wk_lo  + (size_t)rr * 1024; }
  else if (part == 2) { src = Wqkv  + (size_t)(d * 48 + 32 + h) * 1024; dh = Wv_hi  + (size_t)rr * 1024; }
  else                { src = Wout  + (size_t)rr * 1024;                dh = Woutb  + (size_t)rr * 1024; }
  int c = threadIdx.x * 4;
  f32x4 v = *(const f32x4*)&src[c];
  u32 hv[4], lv[4];
#pragma unroll
  for (int j = 0; j < 4; ++j) {
    u16 hb = f32_to_bf16(v[j]);
    hv[j] = hb;
    lv[j] = f32_to_bf16(v[j] - bf16_to_f32(hb));
  }
  uint2 ho; ho.x = hv[0] | (hv[1] << 16); ho.y = hv[2] | (hv[3] << 16);
  *(uint2*)&dh[c] = ho;
  if (dl) {
    uint2 lo; lo.x = lv[0] | (lv[1] << 16); lo.y = lv[2] | (lv[3] << 16);
    *(uint2*)&dl[c] = lo;
  }
}

// ---------------------------------------------------------------------------
// Fused projection GEMM (unchanged from r7). grid (256,3) = 768 blocks.
__global__ __launch_bounds__(256) __attribute__((amdgpu_waves_per_eu(2, 3)))
void proj_fused(const float* __restrict__ x, const float* __restrict__ tx,
                const u16* __restrict__ Wtq_hi, const u16* __restrict__ Wtq_lo,
                const u16* __restrict__ Wk_hi,  const u16* __restrict__ Wk_lo,
                const u16* __restrict__ Wv_hi,
                u16* __restrict__ Qhi, u16* __restrict__ Qlo,
                u16* __restrict__ Khi, u16* __restrict__ Klo,
                u16* __restrict__ Vt, float qscale) {
  __shared__ __align__(16) u16 Ahs[128][40];
  __shared__ __align__(16) u16 Als[128][40];
  __shared__ __align__(16) u16 Bhs[128][40];
  __shared__ __align__(16) u16 Bls[128][40];
  const int tid = threadIdx.x;
  const int wid = tid >> 6, lane = tid & 63;
  const int g = lane >> 4, l16 = lane & 15;
  const int job = blockIdx.y;
  const int tile = blockIdx.x;
  const int wm = (wid & 1) * 64, wn = (wid >> 1) * 64;
  const int K = 1024;

  int m0, n0, N;
  const float* Af;
  const u16 *Bh = nullptr, *Bl = nullptr;
  if (job == 0) { m0 = (tile >> 3) * 128; n0 = (tile & 7) * 128; N = 1024; Af = tx; Bh = Wtq_hi; Bl = Wtq_lo; }
  else if (job == 1) { m0 = (tile >> 3) * 128; n0 = (tile & 7) * 128; N = 1024; Af = x; Bh = Wk_hi; Bl = Wk_lo; }
  else { m0 = (tile >> 5) * 128; n0 = (tile & 31) * 128; N = 4096; Af = x; Bh = Wv_hi; }

  f32x4 acc[4][4];
  const f32x4 zero4 = {0.f, 0.f, 0.f, 0.f};
#pragma unroll
  for (int i = 0; i < 4; ++i)
#pragma unroll
    for (int j = 0; j < 4; ++j) acc[i][j] = zero4;

  uint4 pF[2][2];
  uint4 pU1[2];
  uint4 pU2[2];

#pragma unroll
  for (int r = 0; r < 2; ++r) {
    int idx = tid + r * 256;
    int row = idx >> 2, col = (idx & 3) * 8;
    if (job != 2) {
      const float* ap = &Af[(size_t)(m0 + row) * K + col];
      pF[r][0] = *(const uint4*)ap;
      pF[r][1] = *(const uint4*)(ap + 4);
      pU1[r] = *(const uint4*)&Bh[(size_t)(n0 + row) * K + col];
      pU2[r] = *(const uint4*)&Bl[(size_t)(n0 + row) * K + col];
    } else {
      pU1[r] = *(const uint4*)&Bh[(size_t)(m0 + row) * K + col];
      const float* bp = &Af[(size_t)(n0 + row) * K + col];
      pF[r][0] = *(const uint4*)bp;
      pF[r][1] = *(const uint4*)(bp + 4);
    }
  }

  for (int k0 = 0; k0 < K; k0 += 32) {
    __syncthreads();
#pragma unroll
    for (int r = 0; r < 2; ++r) {
      int idx = tid + r * 256;
      int row = idx >> 2, col = (idx & 3) * 8;
      if (job != 2) {
        uint4 hi, lo;
        split8(pF[r][0], pF[r][1], hi, lo);
        *(uint4*)&Ahs[row][col] = hi;
        *(uint4*)&Als[row][col] = lo;
        *(uint4*)&Bhs[row][col] = pU1[r];
        *(uint4*)&Bls[row][col] = pU2[r];
      } else {
        *(uint4*)&Ahs[row][col] = pU1[r];
        *(uint4*)&Bhs[row][col] = pack_bf16_8(pF[r][0], pF[r][1]);
      }
    }
    __syncthreads();
    if (k0 + 32 < K) {
      int kn = k0 + 32;
#pragma unroll
      for (int r = 0; r < 2; ++r) {
        int idx = tid + r * 256;
        int row = idx >> 2, col = (idx & 3) * 8;
        if (job != 2) {
          const float* ap = &Af[(size_t)(m0 + row) * K + kn + col];
          pF[r][0] = *(const uint4*)ap;
          pF[r][1] = *(const uint4*)(ap + 4);
          pU1[r] = *(const uint4*)&Bh[(size_t)(n0 + row) * K + kn + col];
          pU2[r] = *(const uint4*)&Bl[(size_t)(n0 + row) * K + kn + col];
        } else {
          pU1[r] = *(const uint4*)&Bh[(size_t)(m0 + row) * K + kn + col];
          const float* bp = &Af[(size_t)(n0 + row) * K + kn + col];
          pF[r][0] = *(const uint4*)bp;
          pF[r][1] = *(const uint4*)(bp + 4);
        }
      }
    }
    if (job != 2) {
      short8 ah[4], al[4], bh4[4], bl4[4];
#pragma unroll
      for (int mi = 0; mi < 4; ++mi) {
        ah[mi] = *(const short8*)&Ahs[wm + mi * 16 + l16][g * 8];
        al[mi] = *(const short8*)&Als[wm + mi * 16 + l16][g * 8];
      }
#pragma unroll
      for (int ni = 0; ni < 4; ++ni) {
        bh4[ni] = *(const short8*)&Bhs[wn + ni * 16 + l16][g * 8];
        bl4[ni] = *(const short8*)&Bls[wn + ni * 16 + l16][g * 8];
      }
#pragma unroll
      for (int mi = 0; mi < 4; ++mi)
#pragma unroll
        for (int ni = 0; ni < 4; ++ni) {
          acc[mi][ni] = __builtin_amdgcn_mfma_f32_16x16x32_bf16(ah[mi], bh4[ni], acc[mi][ni], 0, 0, 0);
          acc[mi][ni] = __builtin_amdgcn_mfma_f32_16x16x32_bf16(ah[mi], bl4[ni], acc[mi][ni], 0, 0, 0);
          acc[mi][ni] = __builtin_amdgcn_mfma_f32_16x16x32_bf16(al[mi], bh4[ni], acc[mi][ni], 0, 0, 0);
        }
    } else {
      short8 af[4], bfr[4];
#pragma unroll
      for (int mi = 0; mi < 4; ++mi)
        af[mi] = *(const short8*)&Ahs[wm + mi * 16 + l16][g * 8];
#pragma unroll
      for (int ni = 0; ni < 4; ++ni)
        bfr[ni] = *(const short8*)&Bhs[wn + ni * 16 + l16][g * 8];
#pragma unroll
      for (int mi = 0; mi < 4; ++mi)
#pragma unroll
        for (int ni = 0; ni < 4; ++ni)
          acc[mi][ni] = __builtin_amdgcn_mfma_f32_16x16x32_bf16(af[mi], bfr[ni], acc[mi][ni], 0, 0, 0);
    }
  }

  u16* Chi = (job == 0) ? Qhi : ((job == 1) ? Khi : Vt);
  u16* Clo = (job == 0) ? Qlo : Klo;
  float scale = (job == 0) ? qscale : 1.0f;
#pragma unroll
  for (int mi = 0; mi < 4; ++mi)
#pragma unroll
    for (int ni = 0; ni < 4; ++ni) {
      int row = m0 + wm + mi * 16 + g * 4;
      int col = n0 + wn + ni * 16 + l16;
#pragma unroll
      for (int r = 0; r < 4; ++r) {
        float v = acc[mi][ni][r] * scale;
        size_t o = (size_t)(row + r) * N + col;
        u32 uv = __float_as_uint(v);
        if (job != 2) {
          Chi[o] = (u16)(uv >> 16);
          float lo = v - __uint_as_float(uv & 0xffff0000u);
          Clo[o] = (u16)(__float_as_uint(lo) >> 16);
        } else {
          Chi[o] = (u16)(uv >> 16);
        }
      }
    }
}

// ---------------------------------------------------------------------------
// Final projection (unchanged from r7): C(f32) = A bf16 * B^T bf16.
__global__ __launch_bounds__(256) __attribute__((amdgpu_waves_per_eu(2, 4)))
void gemm_out(const u16* __restrict__ A, const u16* __restrict__ B,
              float* __restrict__ C, int M, int N, int K) {
  __shared__ __align__(16) u16 As[128][40];
  __shared__ __align__(16) u16 Bs[64][40];
  const int tid = threadIdx.x;
  const int wid = tid >> 6, lane = tid & 63;
  const int g = lane >> 4, l16 = lane & 15;
  const int m0 = blockIdx.y * 128, n0 = blockIdx.x * 64;
  const int wm = (wid & 1) * 64, wn = (wid >> 1) * 32;

  f32x4 acc[4][2];
  const f32x4 zero4 = {0.f, 0.f, 0.f, 0.f};
#pragma unroll
  for (int i = 0; i < 4; ++i)
#pragma unroll
    for (int j = 0; j < 2; ++j) acc[i][j] = zero4;

  uint4 pa[2], pb;
  const int rowA0 = tid >> 2, colA = (tid & 3) * 8;
  const int rowA1 = rowA0 + 64;
  const int rowB = tid >> 2, colB = (tid & 3) * 8;
  pa[0] = *(const uint4*)&A[(size_t)(m0 + rowA0) * K + colA];
  pa[1] = *(const uint4*)&A[(size_t)(m0 + rowA1) * K + colA];
  pb    = *(const uint4*)&B[(size_t)(n0 + rowB) * K + colB];

  for (int k0 = 0; k0 < K; k0 += 32) {
    __syncthreads();
    *(uint4*)&As[rowA0][colA] = pa[0];
    *(uint4*)&As[rowA1][colA] = pa[1];
    *(uint4*)&Bs[rowB][colB] = pb;
    __syncthreads();
    if (k0 + 32 < K) {
      pa[0] = *(const uint4*)&A[(size_t)(m0 + rowA0) * K + k0 + 32 + colA];
      pa[1] = *(const uint4*)&A[(size_t)(m0 + rowA1) * K + k0 + 32 + colA];
      pb    = *(const uint4*)&B[(size_t)(n0 + rowB) * K + k0 + 32 + colB];
    }
    short8 af[4], bfr[2];
#pragma unroll
    for (int mi = 0; mi < 4; ++mi)
      af[mi] = *(const short8*)&As[wm + mi * 16 + l16][g * 8];
#pragma unroll
    for (int ni = 0; ni < 2; ++ni)
      bfr[ni] = *(const short8*)&Bs[wn + ni * 16 + l16][g * 8];
#pragma unroll
    for (int mi = 0; mi < 4; ++mi)
#pragma unroll
      for (int ni = 0; ni < 2; ++ni)
        acc[mi][ni] = __builtin_amdgcn_mfma_f32_16x16x32_bf16(af[mi], bfr[ni], acc[mi][ni], 0, 0, 0);
  }
#pragma unroll
  for (int mi = 0; mi < 4; ++mi)
#pragma unroll
    for (int ni = 0; ni < 2; ++ni) {
      int row = m0 + wm + mi * 16 + g * 4;
      int col = n0 + wn + ni * 16 + l16;
#pragma unroll
      for (int r = 0; r < 4; ++r)
        C[(size_t)(row + r) * N + col] = acc[mi][ni][r];
    }
}

// ---------------------------------------------------------------------------
// Flash attention v7: q-tile 128 (4 waves x 32 q), K/V staged via
// global_load_lds (ZERO staging VGPRs), double-buffered, ONE barrier/chunk
// (its implicit vmcnt(0) drain completes the DMA issued a full chunk earlier).
// DMA forces unpadded 128B LDS rows; bank conflicts avoided by source-side
// granule swizzle: lane l fetches global granule (l&7)^(l>>3), so element
// granule gc of row r lands at LDS granule gc^(r&7); reads apply the same XOR.
// Row-sums via an all-ones B-frag held in registers (no LDS ones tile).
__global__ __launch_bounds__(256)
void attn_fwd(const u16* __restrict__ Qhi, const u16* __restrict__ Qlo,
              const u16* __restrict__ Khi, const u16* __restrict__ Klo,
              const u16* __restrict__ Vt, u16* __restrict__ O) {
  const int blk = blockIdx.x;              // 512 blocks
  const int qb = blk & 15, bh = blk >> 4;
  const int h = bh & 15, b = bh >> 4;
  const int t0 = qb * 128;
  const int tid = threadIdx.x, wid = tid >> 6, lane = tid & 63;
  const int g = lane >> 4, l16 = lane & 15;

  __shared__ __align__(16) u16 Ksh[2][64][64];   // keys x d (unpadded, swizzled)
  __shared__ __align__(16) u16 Ksl[2][64][64];
  __shared__ __align__(16) u16 Vs[2][64][64];    // d x keys (unpadded, swizzled)
  __shared__ __align__(16) u16 Ps[4][32][72];    // per-wave P (padded, VALU-written)

  const int lrow = lane >> 3;              // 0..7
  const int lgc  = (lane & 7) ^ lrow;      // swizzled source granule
  const size_t kbase = (size_t)(b * 2048) * 1024 + h * 64;
  const size_t vbase = (size_t)(h * 64) * 4096 + b * 2048;

  // issue async DMA of one 64-key chunk into buffer p (6 instrs, 0 VGPRs held)
  auto issue_chunk = [&](int j0, int p) {
#pragma unroll
    for (int t = 0; t < 2; ++t) {
      int rbase = wid * 16 + t * 8;
      int row = rbase + lrow;
      dma16(&Khi[kbase + (size_t)(j0 + row) * 1024 + lgc * 8], &Ksh[p][rbase][0]);
      dma16(&Klo[kbase + (size_t)(j0 + row) * 1024 + lgc * 8], &Ksl[p][rbase][0]);
      dma16(&Vt[vbase + (size_t)row * 4096 + j0 + lgc * 8],    &Vs[p][rbase][0]);
    }
  };

  // Persistent Q frags: rows t0 + wid*32 + mt*16 + l16, k = ks*32 + g*8 + j
  short8 qh[2][2], ql[2][2];
#pragma unroll
  for (int mt = 0; mt < 2; ++mt)
#pragma unroll
    for (int ks = 0; ks < 2; ++ks) {
      size_t qo = (size_t)(b * 2048 + t0 + wid * 32 + mt * 16 + l16) * 1024
                  + h * 64 + ks * 32 + g * 8;
      qh[mt][ks] = *(const short8*)&Qhi[qo];
      ql[mt][ks] = *(const short8*)&Qlo[qo];
    }

  float mrow[2][4];
#pragma unroll
  for (int mt = 0; mt < 2; ++mt)
#pragma unroll
    for (int r = 0; r < 4; ++r) mrow[mt][r] = -1.0e30f;
  const f32x4 zero4 = {0.f, 0.f, 0.f, 0.f};
  f32x4 acc[2][5];                         // [][4] = row-sum (ones B-frag)
#pragma unroll
  for (int mt = 0; mt < 2; ++mt)
#pragma unroll
    for (int dn = 0; dn < 5; ++dn) acc[mt][dn] = zero4;

  short8 ones8;
#pragma unroll
  for (int j = 0; j < 8; ++j) ones8[j] = (short)0x3f80;   // bf16 1.0

  issue_chunk(0, 0);   // prologue DMA

  for (int i = 0; i < 32; ++i) {
    const int p = i & 1;
    // Drains vmcnt(0): DMA into buf p (issued last iter) complete; also all
    // waves done reading buf 1-p, so it's free for the next DMA.
    __syncthreads();
    if (i < 31) issue_chunk((i + 1) * 64, 1 - p);

    // Scores (log2 domain; Q pre-scaled by 8*log2e). Swizzled granule reads.
    f32x4 s[2][4];
#pragma unroll
    for (int mt = 0; mt < 2; ++mt)
#pragma unroll
      for (int n = 0; n < 4; ++n) s[mt][n] = zero4;
#pragma unroll
    for (int ks = 0; ks < 2; ++ks)
#pragma unroll
      for (int n = 0; n < 4; ++n) {
        int col = (((ks * 4 + g) ^ (l16 & 7))) * 8;
        short8 kh = *(const short8*)&Ksh[p][n * 16 + l16][col];
        short8 kl = *(const short8*)&Ksl[p][n * 16 + l16][col];
        s[0][n] = __builtin_amdgcn_mfma_f32_16x16x32_bf16(qh[0][ks], kh, s[0][n], 0, 0, 0);
        s[1][n] = __builtin_amdgcn_mfma_f32_16x16x32_bf16(qh[1][ks], kh, s[1][n], 0, 0, 0);
        s[0][n] = __builtin_amdgcn_mfma_f32_16x16x32_bf16(ql[0][ks], kh, s[0][n], 0, 0, 0);
        s[1][n] = __builtin_amdgcn_mfma_f32_16x16x32_bf16(ql[1][ks], kh, s[1][n], 0, 0, 0);
        s[0][n] = __builtin_amdgcn_mfma_f32_16x16x32_bf16(qh[0][ks], kl, s[0][n], 0, 0, 0);
        s[1][n] = __builtin_amdgcn_mfma_f32_16x16x32_bf16(qh[1][ks], kl, s[1][n], 0, 0, 0);
      }

    // Online softmax (max only; sums via ones frag). Row (mt, g*4+r).
#pragma unroll
    for (int mt = 0; mt < 2; ++mt)
#pragma unroll
      for (int r = 0; r < 4; ++r) {
        float cm = fmaxf(fmaxf(s[mt][0][r], s[mt][1][r]),
                         fmaxf(s[mt][2][r], s[mt][3][r]));
        cm = fmaxf(cm, __shfl_xor(cm, 1));
        cm = fmaxf(cm, __shfl_xor(cm, 2));
        cm = fmaxf(cm, __shfl_xor(cm, 4));
        cm = fmaxf(cm, __shfl_xor(cm, 8));
        float mnew = fmaxf(mrow[mt][r], cm);
        float al = EXP2F(mrow[mt][r] - mnew);
        mrow[mt][r] = mnew;
#pragma unroll
        for (int dn = 0; dn < 5; ++dn) acc[mt][dn][r] *= al;
        int qr = mt * 16 + g * 4 + r;
#pragma unroll
        for (int n = 0; n < 4; ++n) {
          float pv = EXP2F(s[mt][n][r] - mnew);
          Ps[wid][qr][n * 16 + l16] = (u16)(__float_as_uint(pv) >> 16);
        }
      }

    // PV: P A-frags [m=q][k=key]; Vs B-frags [n=d][k=key] (swizzled);
    // ones8 B-frag accumulates the row-sum column.
#pragma unroll
    for (int ks2 = 0; ks2 < 2; ++ks2) {
      short8 pa0 = *(const short8*)&Ps[wid][l16][ks2 * 32 + g * 8];
      short8 pa1 = *(const short8*)&Ps[wid][16 + l16][ks2 * 32 + g * 8];
#pragma unroll
      for (int dn = 0; dn < 4; ++dn) {
        int col = (((ks2 * 4 + g) ^ (l16 & 7))) * 8;
        short8 vb = *(const short8*)&Vs[p][dn * 16 + l16][col];
        acc[0][dn] = __builtin_amdgcn_mfma_f32_16x16x32_bf16(pa0, vb, acc[0][dn], 0, 0, 0);
        acc[1][dn] = __builtin_amdgcn_mfma_f32_16x16x32_bf16(pa1, vb, acc[1][dn], 0, 0, 0);
      }
      acc[0][4] = __builtin_amdgcn_mfma_f32_16x16x32_bf16(pa0, ones8, acc[0][4], 0, 0, 0);
      acc[1][4] = __builtin_amdgcn_mfma_f32_16x16x32_bf16(pa1, ones8, acc[1][4], 0, 0, 0);
    }
  }

  // Epilogue: O[b, t, h*64+d] bf16 (trunc); l = acc[mt][4]
#pragma unroll
  for (int mt = 0; mt < 2; ++mt)
#pragma unroll
    for (int r = 0; r < 4; ++r) {
      float inv = 1.f / acc[mt][4][r];
      int row = t0 + wid * 32 + mt * 16 + g * 4 + r;
      size_t base = (size_t)(b * 2048 + row) * 1024 + h * 64;
#pragma unroll
      for (int dn = 0; dn < 4; ++dn)
        O[base + dn * 16 + l16] = (u16)(__float_as_uint(acc[mt][dn][r] * inv) >> 16);
    }
}

// ---------------------------------------------------------------------------
extern "C" void kernel_launch(void* const* d_in, const int* in_sizes, int n_in,
                              void* d_out, int out_size, void* d_ws, size_t ws_size,
                              hipStream_t stream) {
  const float* x     = (const float*)d_in[0];
  const float* tx    = (const float*)d_in[1];
  const float* Wqkv  = (const float*)d_in[2];
  const float* Wtqkv = (const float*)d_in[3];
  const float* Wout  = (const float*)d_in[4];
  float* out = (float*)d_out;

  // workspace (peak 52 MB):
  //  0 Wtq_hi | 2 Wtq_lo | 4 Wk_hi | 6 Wk_lo | 8 Wv_hi | 10 Wout_b  (MB)
  //  12 Qhi 8 | 20 Qlo 8 | 28 Khi 8 | 36 Klo 8 | 44 Vt 8
  //  Ob (8MB) aliases 0-8 (weight planes dead after projections)
  char* ws = (char*)d_ws;
  const size_t MB = 1048576;
  u16* Wtq_hi = (u16*)(ws + 0 * MB);
  u16* Wtq_lo = (u16*)(ws + 2 * MB);
  u16* Wk_hi  = (u16*)(ws + 4 * MB);
  u16* Wk_lo  = (u16*)(ws + 6 * MB);
  u16* Wv_hi  = (u16*)(ws + 8 * MB);
  u16* Woutb  = (u16*)(ws + 10 * MB);
  u16* Qhi    = (u16*)(ws + 12 * MB);
  u16* Qlo    = (u16*)(ws + 20 * MB);
  u16* Khi    = (u16*)(ws + 28 * MB);
  u16* Klo    = (u16*)(ws + 36 * MB);
  u16* Vt     = (u16*)(ws + 44 * MB);
  u16* Ob     = (u16*)(ws + 0 * MB);
  if (ws_size < 52 * MB) return;

  const float QSCALE = 8.0f * 1.4426950408889634f;  // sqrt(d)=8, log2(e)

  repack_w<<<4096, 256, 0, stream>>>(Wqkv, Wtqkv, Wout,
                                     Wtq_hi, Wtq_lo, Wk_hi, Wk_lo, Wv_hi, Woutb);
  proj_fused<<<dim3(256, 3), 256, 0, stream>>>(x, tx, Wtq_hi, Wtq_lo, Wk_hi, Wk_lo,
                                               Wv_hi, Qhi, Qlo, Khi, Klo, Vt, QSCALE);
  attn_fwd<<<512, 256, 0, stream>>>(Qhi, Qlo, Khi, Klo, Vt, Ob);
  gemm_out<<<dim3(16, 32), 256, 0, stream>>>(Ob, Woutb, out, 4096, 1024, 1024);
}